// Round 6
// baseline (411.307 us; speedup 1.0000x reference)
//
#include <hip/hip_runtime.h>

#define DIM 128
#define EPS 1e-5f
#define SCAN_TILE 2048  // 256 threads x 8 elements

typedef short s16x8 __attribute__((ext_vector_type(8)));
typedef float f32x4 __attribute__((ext_vector_type(4)));

__device__ __forceinline__ int lower_bound_i(const int* __restrict__ a, int n, int key) {
  int lo = 0, hi = n;
  while (lo < hi) {
    int mid = (lo + hi) >> 1;
    if (a[mid] < key) lo = mid + 1; else hi = mid;
  }
  return lo;
}

__device__ __forceinline__ unsigned rne_bf16(float f) {
  unsigned u = __builtin_bit_cast(unsigned, f);
  return (u + 0x7fffu + ((u >> 16) & 1u)) >> 16;
}
__device__ __forceinline__ float bf16_hi_to_f32(unsigned h) {
  return __builtin_bit_cast(float, h << 16);
}

__device__ __forceinline__ void split_frag(const float* __restrict__ base,
                                           s16x8& hi, s16x8& lo) {
  float4 f0 = *reinterpret_cast<const float4*>(base);
  float4 f1 = *reinterpret_cast<const float4*>(base + 4);
  float v[8] = {f0.x, f0.y, f0.z, f0.w, f1.x, f1.y, f1.z, f1.w};
#pragma unroll
  for (int j = 0; j < 8; ++j) {
    unsigned h = rne_bf16(v[j]);
    float r = v[j] - bf16_hi_to_f32(h);
    hi[j] = (short)h;
    lo[j] = (short)rne_bf16(r);
  }
}

// --- CSR build -------------------------------------------------------------
__global__ __launch_bounds__(256) void hist_kernel(const int* __restrict__ dst,
                                                   int* __restrict__ cnt, int nE) {
  int i = blockIdx.x * 256 + threadIdx.x;
  if (i < nE) atomicAdd(&cnt[dst[i]], 1);
}

// Phase 1: per-block tile sums.
__global__ __launch_bounds__(256) void scan1_kernel(const int* __restrict__ cnt,
                                                    int* __restrict__ bsum, int nN) {
  __shared__ int s[256];
  int t = threadIdx.x;
  int base = blockIdx.x * SCAN_TILE + t * 8;
  int sum = 0;
#pragma unroll
  for (int j = 0; j < 8; ++j) {
    int i = base + j;
    if (i < nN) sum += cnt[i];
  }
  s[t] = sum;
  __syncthreads();
  for (int off = 128; off > 0; off >>= 1) {
    if (t < off) s[t] += s[t + off];
    __syncthreads();
  }
  if (t == 0) bsum[blockIdx.x] = s[0];
}

// Phase 2: serial scan of block sums (nB ~ 25) + write rowptr[nN].
__global__ __launch_bounds__(64) void scan2_kernel(int* __restrict__ bsum,
                                                   int* __restrict__ rowptr,
                                                   int nB, int nN) {
  if (threadIdx.x == 0) {
    int run = 0;
    for (int b = 0; b < nB; ++b) {
      int v = bsum[b];
      bsum[b] = run;
      run += v;
    }
    rowptr[nN] = run;
  }
}

// Phase 3: local exclusive scan within each tile + block offset.
__global__ __launch_bounds__(256) void scan3_kernel(const int* __restrict__ cnt,
                                                    const int* __restrict__ bsum,
                                                    int* __restrict__ rowptr, int nN) {
  __shared__ int s[256];
  int t = threadIdx.x;
  int base = blockIdx.x * SCAN_TILE + t * 8;
  int v[8];
  int tsum = 0;
#pragma unroll
  for (int j = 0; j < 8; ++j) {
    int i = base + j;
    v[j] = (i < nN) ? cnt[i] : 0;
    tsum += v[j];
  }
  s[t] = tsum;
  __syncthreads();
  for (int off = 1; off < 256; off <<= 1) {
    int u = (t >= off) ? s[t - off] : 0;
    __syncthreads();
    s[t] += u;
    __syncthreads();
  }
  int run = bsum[blockIdx.x] + ((t > 0) ? s[t - 1] : 0);
#pragma unroll
  for (int j = 0; j < 8; ++j) {
    int i = base + j;
    if (i < nN) rowptr[i] = run;
    run += v[j];
  }
}

__global__ __launch_bounds__(256) void fill_kernel(const int* __restrict__ src,
    const int* __restrict__ dst, const int* __restrict__ rowptr,
    int* __restrict__ cursor, int* __restrict__ eidx, int nE) {
  int e = blockIdx.x * 256 + threadIdx.x;
  if (e < nE) {
    int d = dst[e];
    int p = atomicAdd(&cursor[d], 1);
    eidx[rowptr[d] + p] = src[e];
  }
}

// --- mean-aggregate via gather: 32 threads per dst node --------------------
__global__ __launch_bounds__(256) void gather_kernel(const float* __restrict__ x,
    const int* __restrict__ rowptr, const int* __restrict__ eidx,
    float* __restrict__ agg, int nN) {
  int grp = (blockIdx.x * 256 + threadIdx.x) >> 5;
  int j = threadIdx.x & 31;
  if (grp >= nN) return;
  int lo = rowptr[grp], hi = rowptr[grp + 1];
  float4 acc = make_float4(0.f, 0.f, 0.f, 0.f);
  int i = lo;
  for (; i + 1 < hi; i += 2) {
    int s0 = eidx[i], s1 = eidx[i + 1];
    float4 v0 = reinterpret_cast<const float4*>(x)[(size_t)s0 * 32 + j];
    float4 v1 = reinterpret_cast<const float4*>(x)[(size_t)s1 * 32 + j];
    acc.x += v0.x; acc.y += v0.y; acc.z += v0.z; acc.w += v0.w;
    acc.x += v1.x; acc.y += v1.y; acc.z += v1.z; acc.w += v1.w;
  }
  if (i < hi) {
    int s0 = eidx[i];
    float4 v0 = reinterpret_cast<const float4*>(x)[(size_t)s0 * 32 + j];
    acc.x += v0.x; acc.y += v0.y; acc.z += v0.z; acc.w += v0.w;
  }
  float invd = 1.0f / fmaxf((float)(hi - lo), 1.0f);
  acc.x *= invd; acc.y *= invd; acc.z *= invd; acc.w *= invd;
  reinterpret_cast<float4*>(agg)[(size_t)grp * 32 + j] = acc;
}

// --- W prep ---------------------------------------------------------------
__global__ __launch_bounds__(256) void cvt_w_kernel(const float* __restrict__ Wl,
    const float* __restrict__ Wr, unsigned short* __restrict__ Wth,
    unsigned short* __restrict__ Wtl) {
  int idx = blockIdx.x * 256 + threadIdx.x;  // c*256 + k
  if (idx >= DIM * 256) return;
  int c = idx >> 8, k = idx & 255;
  float v = (k < DIM) ? Wl[(size_t)k * DIM + c] : Wr[(size_t)(k - DIM) * DIM + c];
  unsigned h = rne_bf16(v);
  float r = v - bf16_hi_to_f32(h);
  Wth[idx] = (unsigned short)h;
  Wtl[idx] = (unsigned short)rne_bf16(r);
}

// --- fused dual-GEMM via bf16 split-precision MFMA --------------------------
// Wave tile: 16 rows x 128 cols; block = 4 waves = 64 rows. Grid ~782 blocks
// (vs 391 with the old 32-row wave tile) -> ~3 blocks/CU for latency hiding.
__global__ __launch_bounds__(256) void gemm_mfma_kernel(
    const float* __restrict__ A0, const float* __restrict__ A1,
    const unsigned short* __restrict__ Wth, const unsigned short* __restrict__ Wtl,
    const float* __restrict__ bias, float* __restrict__ h, int nN) {
  const int lane = threadIdx.x & 63;
  const int wave = threadIdx.x >> 6;
  const int rbase = blockIdx.x * 64 + wave * 16;
  const int lrow = lane & 15;
  const int koff = (lane >> 4) * 8;

  f32x4 acc[8];
#pragma unroll
  for (int ct = 0; ct < 8; ++ct)
    acc[ct] = (f32x4){0.f, 0.f, 0.f, 0.f};

  int r0 = rbase + lrow;
  if (r0 > nN - 1) r0 = nN - 1;

#pragma unroll
  for (int s = 0; s < 2; ++s) {
    const float* A = s ? A1 : A0;
    const float* a0p = A + (size_t)r0 * DIM;
#pragma unroll
    for (int ks = 0; ks < 4; ++ks) {
      int ka = ks * 32 + koff;
      int kw = s * 128 + ka;
      s16x8 ah, al;
      split_frag(a0p + ka, ah, al);
#pragma unroll
      for (int ct = 0; ct < 8; ++ct) {
        int c = ct * 16 + lrow;
        s16x8 wh = *reinterpret_cast<const s16x8*>(Wth + (size_t)c * 256 + kw);
        s16x8 wl = *reinterpret_cast<const s16x8*>(Wtl + (size_t)c * 256 + kw);
        acc[ct] = __builtin_amdgcn_mfma_f32_16x16x32_bf16(ah, wh, acc[ct], 0, 0, 0);
        acc[ct] = __builtin_amdgcn_mfma_f32_16x16x32_bf16(ah, wl, acc[ct], 0, 0, 0);
        acc[ct] = __builtin_amdgcn_mfma_f32_16x16x32_bf16(al, wh, acc[ct], 0, 0, 0);
      }
    }
  }

#pragma unroll
  for (int ct = 0; ct < 8; ++ct) {
    int c = ct * 16 + lrow;
    float b = bias[c];
    int rr = rbase + (lane >> 4) * 4;
#pragma unroll
    for (int j = 0; j < 4; ++j) {
      int row = rr + j;
      if (row < nN) h[(size_t)row * DIM + c] = acc[ct][j] + b;
    }
  }
}

__global__ __launch_bounds__(256) void stats_kernel(const float* __restrict__ h,
                                                    float* __restrict__ sums, int nN) {
  __shared__ float s_s[256];
  __shared__ float s_q[256];
  int tid = threadIdx.x;
  int c = tid & 127;
  int rp = tid >> 7;
  float ls = 0.f, lq = 0.f;
  for (int r = blockIdx.x * 2 + rp; r < nN; r += gridDim.x * 2) {
    float v = h[(size_t)r * DIM + c];
    ls += v;
    lq += v * v;
  }
  s_s[tid] = ls;
  s_q[tid] = lq;
  __syncthreads();
  if (tid < 128) {
    atomicAdd(&sums[c], s_s[tid] + s_s[tid + 128]);
    atomicAdd(&sums[DIM + c], s_q[tid] + s_q[tid + 128]);
  }
}

__global__ __launch_bounds__(256) void bn_relu_kernel(const float* __restrict__ h,
    const float* __restrict__ sums, const float* __restrict__ gamma,
    const float* __restrict__ beta, float* __restrict__ xout, int nN) {
  int idx = blockIdx.x * 256 + threadIdx.x;
  int total = nN * (DIM / 4);
  if (idx >= total) return;
  int c = (idx & 31) * 4;
  float invN = 1.0f / (float)nN;
  float4 hv = reinterpret_cast<const float4*>(h)[idx];
  const float* hp = reinterpret_cast<const float*>(&hv);
  float4 o;
  float* op = reinterpret_cast<float*>(&o);
#pragma unroll
  for (int j = 0; j < 4; ++j) {
    float mu = sums[c + j] * invN;
    float var = sums[DIM + c + j] * invN - mu * mu;
    float sc = gamma[c + j] * rsqrtf(var + EPS);
    float sh = beta[c + j] - mu * sc;
    op[j] = fmaxf(hp[j] * sc + sh, 0.0f);
  }
  reinterpret_cast<float4*>(xout)[idx] = o;
}

// --- fused final BN+ReLU + segmented mean-pool ------------------------------
#define POOL_ROWS 32
__global__ __launch_bounds__(256) void pool_fused_kernel(const float* __restrict__ h,
    const float* __restrict__ sums, const float* __restrict__ gamma,
    const float* __restrict__ beta, const int* __restrict__ batch,
    float* __restrict__ outsum, int nN) {
  int c = threadIdx.x & 127;
  int rp = threadIdx.x >> 7;
  int r0 = blockIdx.x * POOL_ROWS;
  float invN = 1.0f / (float)nN;
  float mu = sums[c] * invN;
  float var = sums[DIM + c] * invN - mu * mu;
  float sc = gamma[c] * rsqrtf(var + EPS);
  float sh = beta[c] - mu * sc;
  int rend = min(r0 + POOL_ROWS, nN);
  float acc = 0.f;
  int cur = -1;
  for (int r = r0 + rp; r < rend; r += 2) {
    int g = batch[r];
    float v = fmaxf(h[(size_t)r * DIM + c] * sc + sh, 0.0f);
    if (g != cur) {
      if (cur >= 0) atomicAdd(&outsum[(size_t)cur * DIM + c], acc);
      cur = g; acc = 0.f;
    }
    acc += v;
  }
  if (cur >= 0) atomicAdd(&outsum[(size_t)cur * DIM + c], acc);
}

__global__ __launch_bounds__(256) void pool_div_kernel(const float* __restrict__ outsum,
    const int* __restrict__ batch, float* __restrict__ out, int nN, int nG) {
  int idx = blockIdx.x * 256 + threadIdx.x;  // g*128 + c
  if (idx >= nG * DIM) return;
  int g = idx >> 7;
  int lo = lower_bound_i(batch, nN, g);
  int hi = lower_bound_i(batch, nN, g + 1);
  float cnt = fmaxf((float)(hi - lo), 1.0f);
  out[idx] = outsum[idx] / cnt;
}

extern "C" void kernel_launch(void* const* d_in, const int* in_sizes, int n_in,
                              void* d_out, int out_size, void* d_ws, size_t ws_size,
                              hipStream_t stream) {
  const float* x     = (const float*)d_in[0];
  const int*   ei    = (const int*)d_in[1];
  const int*   batch = (const int*)d_in[2];
  const float* W_l   = (const float*)d_in[3];
  const float* b_l   = (const float*)d_in[4];
  const float* W_r   = (const float*)d_in[5];
  const float* gamma = (const float*)d_in[6];
  const float* beta  = (const float*)d_in[7];
  float* out = (float*)d_out;

  const int N = in_sizes[2];
  const int E = in_sizes[1] / 2;
  const int G = out_size / DIM;
  const int L = in_sizes[3] / (DIM * DIM);

  const int* src  = ei;
  const int* dstE = ei + E;

  const int nB = (N + SCAN_TILE - 1) / SCAN_TILE;

  // workspace layout
  char* wsb = (char*)d_ws;
  float* agg    = (float*)wsb;  wsb += (size_t)N * DIM * sizeof(float);
  float* h      = (float*)wsb;  wsb += (size_t)N * DIM * sizeof(float);
  float* xb     = (float*)wsb;  wsb += (size_t)N * DIM * sizeof(float);
  float* sums   = (float*)wsb;  wsb += 2 * DIM * sizeof(float);
  float* outsum = (float*)wsb;  wsb += (size_t)G * DIM * sizeof(float);
  int* cnt    = (int*)wsb;      wsb += (size_t)N * sizeof(int);
  int* rowptr = (int*)wsb;      wsb += (size_t)(N + 1) * sizeof(int);
  int* cursor = (int*)wsb;      wsb += (size_t)N * sizeof(int);
  int* bsum   = (int*)wsb;      wsb += (size_t)nB * sizeof(int);
  int* eidx   = (int*)wsb;      wsb += (size_t)E * sizeof(int);
  unsigned short* Wth = (unsigned short*)wsb; wsb += (size_t)DIM * 256 * sizeof(unsigned short);
  unsigned short* Wtl = (unsigned short*)wsb; wsb += (size_t)DIM * 256 * sizeof(unsigned short);

  // CSR build
  hipMemsetAsync(cnt, 0, (size_t)N * sizeof(int), stream);
  hipMemsetAsync(cursor, 0, (size_t)N * sizeof(int), stream);
  hist_kernel<<<(E + 255) / 256, 256, 0, stream>>>(dstE, cnt, E);
  scan1_kernel<<<nB, 256, 0, stream>>>(cnt, bsum, N);
  scan2_kernel<<<1, 64, 0, stream>>>(bsum, rowptr, nB, N);
  scan3_kernel<<<nB, 256, 0, stream>>>(cnt, bsum, rowptr, N);
  fill_kernel<<<(E + 255) / 256, 256, 0, stream>>>(src, dstE, rowptr, cursor, eidx, E);

  const float* xin = x;
  for (int l = 0; l < L; ++l) {
    cvt_w_kernel<<<(DIM * 256 + 255) / 256, 256, 0, stream>>>(
        W_l + (size_t)l * DIM * DIM, W_r + (size_t)l * DIM * DIM, Wth, Wtl);
    gather_kernel<<<(N * 32 + 255) / 256, 256, 0, stream>>>(xin, rowptr, eidx, agg, N);
    gemm_mfma_kernel<<<(N + 63) / 64, 256, 0, stream>>>(agg, xin, Wth, Wtl,
        b_l + (size_t)l * DIM, h, N);
    hipMemsetAsync(sums, 0, 2 * DIM * sizeof(float), stream);
    stats_kernel<<<240, 256, 0, stream>>>(h, sums, N);
    if (l < L - 1) {
      bn_relu_kernel<<<(N * (DIM / 4) + 255) / 256, 256, 0, stream>>>(
          h, sums, gamma + (size_t)l * DIM, beta + (size_t)l * DIM, xb, N);
      xin = xb;
    } else {
      hipMemsetAsync(outsum, 0, (size_t)G * DIM * sizeof(float), stream);
      pool_fused_kernel<<<(N + POOL_ROWS - 1) / POOL_ROWS, 256, 0, stream>>>(
          h, sums, gamma + (size_t)l * DIM, beta + (size_t)l * DIM, batch, outsum, N);
      pool_div_kernel<<<(G * DIM + 255) / 256, 256, 0, stream>>>(outsum, batch, out, N, G);
    }
  }
}

// Round 7
// 321.830 us; speedup vs baseline: 1.2780x; 1.2780x over previous
//
#include <hip/hip_runtime.h>

#define DIM 128
#define EPS 1e-5f
#define SCAN_TILE 2048  // 256 threads x 8 elements

typedef short s16x8 __attribute__((ext_vector_type(8)));
typedef float f32x4 __attribute__((ext_vector_type(4)));

__device__ __forceinline__ int lower_bound_i(const int* __restrict__ a, int n, int key) {
  int lo = 0, hi = n;
  while (lo < hi) {
    int mid = (lo + hi) >> 1;
    if (a[mid] < key) lo = mid + 1; else hi = mid;
  }
  return lo;
}

__device__ __forceinline__ unsigned rne_bf16(float f) {
  unsigned u = __builtin_bit_cast(unsigned, f);
  return (u + 0x7fffu + ((u >> 16) & 1u)) >> 16;
}
__device__ __forceinline__ float bf16_hi_to_f32(unsigned h) {
  return __builtin_bit_cast(float, h << 16);
}

__device__ __forceinline__ void split_frag(const float* __restrict__ base,
                                           s16x8& hi, s16x8& lo) {
  float4 f0 = *reinterpret_cast<const float4*>(base);
  float4 f1 = *reinterpret_cast<const float4*>(base + 4);
  float v[8] = {f0.x, f0.y, f0.z, f0.w, f1.x, f1.y, f1.z, f1.w};
#pragma unroll
  for (int j = 0; j < 8; ++j) {
    unsigned h = rne_bf16(v[j]);
    float r = v[j] - bf16_hi_to_f32(h);
    hi[j] = (short)h;
    lo[j] = (short)rne_bf16(r);
  }
}

// --- CSR build -------------------------------------------------------------
__global__ __launch_bounds__(256) void hist_kernel(const int* __restrict__ dst,
                                                   int* __restrict__ cnt, int nE) {
  int i = blockIdx.x * 256 + threadIdx.x;
  if (i < nE) atomicAdd(&cnt[dst[i]], 1);
}

__global__ __launch_bounds__(256) void scan1_kernel(const int* __restrict__ cnt,
                                                    int* __restrict__ bsum, int nN) {
  __shared__ int s[256];
  int t = threadIdx.x;
  int base = blockIdx.x * SCAN_TILE + t * 8;
  int sum = 0;
#pragma unroll
  for (int j = 0; j < 8; ++j) {
    int i = base + j;
    if (i < nN) sum += cnt[i];
  }
  s[t] = sum;
  __syncthreads();
  for (int off = 128; off > 0; off >>= 1) {
    if (t < off) s[t] += s[t + off];
    __syncthreads();
  }
  if (t == 0) bsum[blockIdx.x] = s[0];
}

__global__ __launch_bounds__(64) void scan2_kernel(int* __restrict__ bsum,
                                                   int* __restrict__ rowptr,
                                                   int nB, int nN) {
  if (threadIdx.x == 0) {
    int run = 0;
    for (int b = 0; b < nB; ++b) {
      int v = bsum[b];
      bsum[b] = run;
      run += v;
    }
    rowptr[nN] = run;
  }
}

__global__ __launch_bounds__(256) void scan3_kernel(const int* __restrict__ cnt,
                                                    const int* __restrict__ bsum,
                                                    int* __restrict__ rowptr, int nN) {
  __shared__ int s[256];
  int t = threadIdx.x;
  int base = blockIdx.x * SCAN_TILE + t * 8;
  int v[8];
  int tsum = 0;
#pragma unroll
  for (int j = 0; j < 8; ++j) {
    int i = base + j;
    v[j] = (i < nN) ? cnt[i] : 0;
    tsum += v[j];
  }
  s[t] = tsum;
  __syncthreads();
  for (int off = 1; off < 256; off <<= 1) {
    int u = (t >= off) ? s[t - off] : 0;
    __syncthreads();
    s[t] += u;
    __syncthreads();
  }
  int run = bsum[blockIdx.x] + ((t > 0) ? s[t - 1] : 0);
#pragma unroll
  for (int j = 0; j < 8; ++j) {
    int i = base + j;
    if (i < nN) rowptr[i] = run;
    run += v[j];
  }
}

__global__ __launch_bounds__(256) void fill_kernel(const int* __restrict__ src,
    const int* __restrict__ dst, const int* __restrict__ rowptr,
    int* __restrict__ cursor, int* __restrict__ eidx, int nE) {
  int e = blockIdx.x * 256 + threadIdx.x;
  if (e < nE) {
    int d = dst[e];
    int p = atomicAdd(&cursor[d], 1);
    eidx[rowptr[d] + p] = src[e];
  }
}

// --- mean-aggregate via gather: 32 threads per dst node --------------------
__global__ __launch_bounds__(256) void gather_kernel(const float* __restrict__ x,
    const int* __restrict__ rowptr, const int* __restrict__ eidx,
    float* __restrict__ agg, int nN) {
  int grp = (blockIdx.x * 256 + threadIdx.x) >> 5;
  int j = threadIdx.x & 31;
  if (grp >= nN) return;
  int lo = rowptr[grp], hi = rowptr[grp + 1];
  float4 acc = make_float4(0.f, 0.f, 0.f, 0.f);
  int i = lo;
  for (; i + 1 < hi; i += 2) {
    int s0 = eidx[i], s1 = eidx[i + 1];
    float4 v0 = reinterpret_cast<const float4*>(x)[(size_t)s0 * 32 + j];
    float4 v1 = reinterpret_cast<const float4*>(x)[(size_t)s1 * 32 + j];
    acc.x += v0.x; acc.y += v0.y; acc.z += v0.z; acc.w += v0.w;
    acc.x += v1.x; acc.y += v1.y; acc.z += v1.z; acc.w += v1.w;
  }
  if (i < hi) {
    int s0 = eidx[i];
    float4 v0 = reinterpret_cast<const float4*>(x)[(size_t)s0 * 32 + j];
    acc.x += v0.x; acc.y += v0.y; acc.z += v0.z; acc.w += v0.w;
  }
  float invd = 1.0f / fmaxf((float)(hi - lo), 1.0f);
  acc.x *= invd; acc.y *= invd; acc.z *= invd; acc.w *= invd;
  reinterpret_cast<float4*>(agg)[(size_t)grp * 32 + j] = acc;
}

// --- W prep ---------------------------------------------------------------
__global__ __launch_bounds__(256) void cvt_w_kernel(const float* __restrict__ Wl,
    const float* __restrict__ Wr, unsigned short* __restrict__ Wth,
    unsigned short* __restrict__ Wtl) {
  int idx = blockIdx.x * 256 + threadIdx.x;  // c*256 + k
  if (idx >= DIM * 256) return;
  int c = idx >> 8, k = idx & 255;
  float v = (k < DIM) ? Wl[(size_t)k * DIM + c] : Wr[(size_t)(k - DIM) * DIM + c];
  unsigned h = rne_bf16(v);
  float r = v - bf16_hi_to_f32(h);
  Wth[idx] = (unsigned short)h;
  Wtl[idx] = (unsigned short)rne_bf16(r);
}

// --- fused dual-GEMM via bf16 split-precision MFMA + LDS-staged W ----------
// Block: 256 threads = 4 waves; wave tile 32 rows x 128 cols (rt=2).
// Two phases (s=0: agg @ W[:,0:128], s=1: x @ W[:,128:256]); per phase the
// 64KB W-half (hi+lo) is staged to LDS with a (c&7)<<4 byte-XOR swizzle so
// each quarter-wave's 16 b128 reads hit 8 distinct 16B slots (b128 optimum).
__global__ __launch_bounds__(256) void gemm_mfma_kernel(
    const float* __restrict__ A0, const float* __restrict__ A1,
    const unsigned short* __restrict__ Wth, const unsigned short* __restrict__ Wtl,
    const float* __restrict__ bias, float* __restrict__ h, int nN) {
  __shared__ unsigned short Wh_lds[DIM * 128];  // 32KB, [c][k] swizzled
  __shared__ unsigned short Wl_lds[DIM * 128];  // 32KB
  const int tid = threadIdx.x;
  const int lane = tid & 63;
  const int wave = tid >> 6;
  const int rbase = blockIdx.x * 128 + wave * 32;
  const int lrow = lane & 15;
  const int koff = (lane >> 4) * 8;

  f32x4 acc[2][8];
#pragma unroll
  for (int rt = 0; rt < 2; ++rt)
#pragma unroll
    for (int ct = 0; ct < 8; ++ct)
      acc[rt][ct] = (f32x4){0.f, 0.f, 0.f, 0.f};

  int r0 = rbase + lrow;      if (r0 > nN - 1) r0 = nN - 1;
  int r1 = rbase + 16 + lrow; if (r1 > nN - 1) r1 = nN - 1;

#pragma unroll
  for (int s = 0; s < 2; ++s) {
    // stage W half s: 128 cols x 128 k (hi+lo) = 2048 16B chunks each
    __syncthreads();  // protect prior phase's reads before overwrite
#pragma unroll
    for (int i = 0; i < 8; ++i) {
      int idx = i * 256 + tid;   // 0..2047
      int c = idx >> 4;
      int kc = idx & 15;         // 16B chunk within col
      int lb = c * 256 + ((kc * 16) ^ ((c & 7) << 4));  // swizzled byte addr
      float4 hv = *reinterpret_cast<const float4*>(Wth + (size_t)c * 256 + s * 128 + kc * 8);
      float4 lv = *reinterpret_cast<const float4*>(Wtl + (size_t)c * 256 + s * 128 + kc * 8);
      *reinterpret_cast<float4*>(reinterpret_cast<char*>(Wh_lds) + lb) = hv;
      *reinterpret_cast<float4*>(reinterpret_cast<char*>(Wl_lds) + lb) = lv;
    }
    __syncthreads();

    const float* A = s ? A1 : A0;
    const float* a0p = A + (size_t)r0 * DIM;
    const float* a1p = A + (size_t)r1 * DIM;
#pragma unroll
    for (int ks = 0; ks < 4; ++ks) {
      int ka = ks * 32 + koff;   // k within this half (0..127)
      s16x8 ah0, al0, ah1, al1;
      split_frag(a0p + ka, ah0, al0);
      split_frag(a1p + ka, ah1, al1);
#pragma unroll
      for (int ct = 0; ct < 8; ++ct) {
        int c = ct * 16 + lrow;
        int lb = c * 256 + ((ka * 2) ^ ((c & 7) << 4));
        s16x8 wh = *reinterpret_cast<const s16x8*>(reinterpret_cast<const char*>(Wh_lds) + lb);
        s16x8 wl = *reinterpret_cast<const s16x8*>(reinterpret_cast<const char*>(Wl_lds) + lb);
        acc[0][ct] = __builtin_amdgcn_mfma_f32_16x16x32_bf16(ah0, wh, acc[0][ct], 0, 0, 0);
        acc[0][ct] = __builtin_amdgcn_mfma_f32_16x16x32_bf16(ah0, wl, acc[0][ct], 0, 0, 0);
        acc[0][ct] = __builtin_amdgcn_mfma_f32_16x16x32_bf16(al0, wh, acc[0][ct], 0, 0, 0);
        acc[1][ct] = __builtin_amdgcn_mfma_f32_16x16x32_bf16(ah1, wh, acc[1][ct], 0, 0, 0);
        acc[1][ct] = __builtin_amdgcn_mfma_f32_16x16x32_bf16(ah1, wl, acc[1][ct], 0, 0, 0);
        acc[1][ct] = __builtin_amdgcn_mfma_f32_16x16x32_bf16(al1, wh, acc[1][ct], 0, 0, 0);
      }
    }
  }

#pragma unroll
  for (int ct = 0; ct < 8; ++ct) {
    int c = ct * 16 + lrow;
    float b = bias[c];
#pragma unroll
    for (int rt = 0; rt < 2; ++rt) {
      int rr = rbase + rt * 16 + (lane >> 4) * 4;
#pragma unroll
      for (int j = 0; j < 4; ++j) {
        int row = rr + j;
        if (row < nN) h[(size_t)row * DIM + c] = acc[rt][ct][j] + b;
      }
    }
  }
}

__global__ __launch_bounds__(256) void stats_kernel(const float* __restrict__ h,
                                                    float* __restrict__ sums, int nN) {
  __shared__ float s_s[256];
  __shared__ float s_q[256];
  int tid = threadIdx.x;
  int c = tid & 127;
  int rp = tid >> 7;
  float ls = 0.f, lq = 0.f;
  for (int r = blockIdx.x * 2 + rp; r < nN; r += gridDim.x * 2) {
    float v = h[(size_t)r * DIM + c];
    ls += v;
    lq += v * v;
  }
  s_s[tid] = ls;
  s_q[tid] = lq;
  __syncthreads();
  if (tid < 128) {
    atomicAdd(&sums[c], s_s[tid] + s_s[tid + 128]);
    atomicAdd(&sums[DIM + c], s_q[tid] + s_q[tid + 128]);
  }
}

__global__ __launch_bounds__(256) void bn_relu_kernel(const float* __restrict__ h,
    const float* __restrict__ sums, const float* __restrict__ gamma,
    const float* __restrict__ beta, float* __restrict__ xout, int nN) {
  int idx = blockIdx.x * 256 + threadIdx.x;
  int total = nN * (DIM / 4);
  if (idx >= total) return;
  int c = (idx & 31) * 4;
  float invN = 1.0f / (float)nN;
  float4 hv = reinterpret_cast<const float4*>(h)[idx];
  const float* hp = reinterpret_cast<const float*>(&hv);
  float4 o;
  float* op = reinterpret_cast<float*>(&o);
#pragma unroll
  for (int j = 0; j < 4; ++j) {
    float mu = sums[c + j] * invN;
    float var = sums[DIM + c + j] * invN - mu * mu;
    float sc = gamma[c + j] * rsqrtf(var + EPS);
    float sh = beta[c + j] - mu * sc;
    op[j] = fmaxf(hp[j] * sc + sh, 0.0f);
  }
  reinterpret_cast<float4*>(xout)[idx] = o;
}

// --- fused final BN+ReLU + segmented mean-pool ------------------------------
#define POOL_ROWS 32
__global__ __launch_bounds__(256) void pool_fused_kernel(const float* __restrict__ h,
    const float* __restrict__ sums, const float* __restrict__ gamma,
    const float* __restrict__ beta, const int* __restrict__ batch,
    float* __restrict__ outsum, int nN) {
  int c = threadIdx.x & 127;
  int rp = threadIdx.x >> 7;
  int r0 = blockIdx.x * POOL_ROWS;
  float invN = 1.0f / (float)nN;
  float mu = sums[c] * invN;
  float var = sums[DIM + c] * invN - mu * mu;
  float sc = gamma[c] * rsqrtf(var + EPS);
  float sh = beta[c] - mu * sc;
  int rend = min(r0 + POOL_ROWS, nN);
  float acc = 0.f;
  int cur = -1;
  for (int r = r0 + rp; r < rend; r += 2) {
    int g = batch[r];
    float v = fmaxf(h[(size_t)r * DIM + c] * sc + sh, 0.0f);
    if (g != cur) {
      if (cur >= 0) atomicAdd(&outsum[(size_t)cur * DIM + c], acc);
      cur = g; acc = 0.f;
    }
    acc += v;
  }
  if (cur >= 0) atomicAdd(&outsum[(size_t)cur * DIM + c], acc);
}

__global__ __launch_bounds__(256) void pool_div_kernel(const float* __restrict__ outsum,
    const int* __restrict__ batch, float* __restrict__ out, int nN, int nG) {
  int idx = blockIdx.x * 256 + threadIdx.x;  // g*128 + c
  if (idx >= nG * DIM) return;
  int g = idx >> 7;
  int lo = lower_bound_i(batch, nN, g);
  int hi = lower_bound_i(batch, nN, g + 1);
  float cnt = fmaxf((float)(hi - lo), 1.0f);
  out[idx] = outsum[idx] / cnt;
}

extern "C" void kernel_launch(void* const* d_in, const int* in_sizes, int n_in,
                              void* d_out, int out_size, void* d_ws, size_t ws_size,
                              hipStream_t stream) {
  const float* x     = (const float*)d_in[0];
  const int*   ei    = (const int*)d_in[1];
  const int*   batch = (const int*)d_in[2];
  const float* W_l   = (const float*)d_in[3];
  const float* b_l   = (const float*)d_in[4];
  const float* W_r   = (const float*)d_in[5];
  const float* gamma = (const float*)d_in[6];
  const float* beta  = (const float*)d_in[7];
  float* out = (float*)d_out;

  const int N = in_sizes[2];
  const int E = in_sizes[1] / 2;
  const int G = out_size / DIM;
  const int L = in_sizes[3] / (DIM * DIM);

  const int* src  = ei;
  const int* dstE = ei + E;

  const int nB = (N + SCAN_TILE - 1) / SCAN_TILE;

  // workspace layout
  char* wsb = (char*)d_ws;
  float* agg    = (float*)wsb;  wsb += (size_t)N * DIM * sizeof(float);
  float* h      = (float*)wsb;  wsb += (size_t)N * DIM * sizeof(float);
  float* xb     = (float*)wsb;  wsb += (size_t)N * DIM * sizeof(float);
  float* sums   = (float*)wsb;  wsb += 2 * DIM * sizeof(float);
  float* outsum = (float*)wsb;  wsb += (size_t)G * DIM * sizeof(float);
  int* cnt    = (int*)wsb;      wsb += (size_t)N * sizeof(int);
  int* rowptr = (int*)wsb;      wsb += (size_t)(N + 1) * sizeof(int);
  int* cursor = (int*)wsb;      wsb += (size_t)N * sizeof(int);
  int* bsum   = (int*)wsb;      wsb += (size_t)nB * sizeof(int);
  int* eidx   = (int*)wsb;      wsb += (size_t)E * sizeof(int);
  unsigned short* Wth = (unsigned short*)wsb; wsb += (size_t)DIM * 256 * sizeof(unsigned short);
  unsigned short* Wtl = (unsigned short*)wsb; wsb += (size_t)DIM * 256 * sizeof(unsigned short);

  // CSR build
  hipMemsetAsync(cnt, 0, (size_t)N * sizeof(int), stream);
  hipMemsetAsync(cursor, 0, (size_t)N * sizeof(int), stream);
  hist_kernel<<<(E + 255) / 256, 256, 0, stream>>>(dstE, cnt, E);
  scan1_kernel<<<nB, 256, 0, stream>>>(cnt, bsum, N);
  scan2_kernel<<<1, 64, 0, stream>>>(bsum, rowptr, nB, N);
  scan3_kernel<<<nB, 256, 0, stream>>>(cnt, bsum, rowptr, N);
  fill_kernel<<<(E + 255) / 256, 256, 0, stream>>>(src, dstE, rowptr, cursor, eidx, E);

  const float* xin = x;
  for (int l = 0; l < L; ++l) {
    cvt_w_kernel<<<(DIM * 256 + 255) / 256, 256, 0, stream>>>(
        W_l + (size_t)l * DIM * DIM, W_r + (size_t)l * DIM * DIM, Wth, Wtl);
    gather_kernel<<<(N * 32 + 255) / 256, 256, 0, stream>>>(xin, rowptr, eidx, agg, N);
    gemm_mfma_kernel<<<(N + 127) / 128, 256, 0, stream>>>(agg, xin, Wth, Wtl,
        b_l + (size_t)l * DIM, h, N);
    hipMemsetAsync(sums, 0, 2 * DIM * sizeof(float), stream);
    stats_kernel<<<240, 256, 0, stream>>>(h, sums, N);
    if (l < L - 1) {
      bn_relu_kernel<<<(N * (DIM / 4) + 255) / 256, 256, 0, stream>>>(
          h, sums, gamma + (size_t)l * DIM, beta + (size_t)l * DIM, xb, N);
      xin = xb;
    } else {
      hipMemsetAsync(outsum, 0, (size_t)G * DIM * sizeof(float), stream);
      pool_fused_kernel<<<(N + POOL_ROWS - 1) / POOL_ROWS, 256, 0, stream>>>(
          h, sums, gamma + (size_t)l * DIM, beta + (size_t)l * DIM, batch, outsum, N);
      pool_div_kernel<<<(G * DIM + 255) / 256, 256, 0, stream>>>(outsum, batch, out, N, G);
    }
  }
}

// Round 8
// 305.062 us; speedup vs baseline: 1.3483x; 1.0550x over previous
//
#include <hip/hip_runtime.h>

#define DIM 128
#define EPS 1e-5f
#define SCAN_TILE 2048  // 256 threads x 8 elements

typedef short s16x8 __attribute__((ext_vector_type(8)));
typedef unsigned short u16x8 __attribute__((ext_vector_type(8)));
typedef unsigned short u16x4 __attribute__((ext_vector_type(4)));
typedef float f32x4 __attribute__((ext_vector_type(4)));

__device__ __forceinline__ int lower_bound_i(const int* __restrict__ a, int n, int key) {
  int lo = 0, hi = n;
  while (lo < hi) {
    int mid = (lo + hi) >> 1;
    if (a[mid] < key) lo = mid + 1; else hi = mid;
  }
  return lo;
}

__device__ __forceinline__ unsigned rne_bf16(float f) {
  unsigned u = __builtin_bit_cast(unsigned, f);
  return (u + 0x7fffu + ((u >> 16) & 1u)) >> 16;
}
__device__ __forceinline__ float bf16_hi_to_f32(unsigned h) {
  return __builtin_bit_cast(float, h << 16);
}

__device__ __forceinline__ void split_frag(const float* __restrict__ base,
                                           s16x8& hi, s16x8& lo) {
  float4 f0 = *reinterpret_cast<const float4*>(base);
  float4 f1 = *reinterpret_cast<const float4*>(base + 4);
  float v[8] = {f0.x, f0.y, f0.z, f0.w, f1.x, f1.y, f1.z, f1.w};
#pragma unroll
  for (int j = 0; j < 8; ++j) {
    unsigned h = rne_bf16(v[j]);
    float r = v[j] - bf16_hi_to_f32(h);
    hi[j] = (short)h;
    lo[j] = (short)rne_bf16(r);
  }
}

// --- CSR build -------------------------------------------------------------
__global__ __launch_bounds__(256) void hist_kernel(const int* __restrict__ dst,
                                                   int* __restrict__ cnt, int nE) {
  int i = blockIdx.x * 256 + threadIdx.x;
  if (i < nE) atomicAdd(&cnt[dst[i]], 1);
}

__global__ __launch_bounds__(256) void scan1_kernel(const int* __restrict__ cnt,
                                                    int* __restrict__ bsum, int nN) {
  __shared__ int s[256];
  int t = threadIdx.x;
  int base = blockIdx.x * SCAN_TILE + t * 8;
  int sum = 0;
#pragma unroll
  for (int j = 0; j < 8; ++j) {
    int i = base + j;
    if (i < nN) sum += cnt[i];
  }
  s[t] = sum;
  __syncthreads();
  for (int off = 128; off > 0; off >>= 1) {
    if (t < off) s[t] += s[t + off];
    __syncthreads();
  }
  if (t == 0) bsum[blockIdx.x] = s[0];
}

__global__ __launch_bounds__(64) void scan2_kernel(int* __restrict__ bsum,
                                                   int* __restrict__ rowptr,
                                                   int nB, int nN) {
  if (threadIdx.x == 0) {
    int run = 0;
    for (int b = 0; b < nB; ++b) {
      int v = bsum[b];
      bsum[b] = run;
      run += v;
    }
    rowptr[nN] = run;
  }
}

__global__ __launch_bounds__(256) void scan3_kernel(const int* __restrict__ cnt,
                                                    const int* __restrict__ bsum,
                                                    int* __restrict__ rowptr, int nN) {
  __shared__ int s[256];
  int t = threadIdx.x;
  int base = blockIdx.x * SCAN_TILE + t * 8;
  int v[8];
  int tsum = 0;
#pragma unroll
  for (int j = 0; j < 8; ++j) {
    int i = base + j;
    v[j] = (i < nN) ? cnt[i] : 0;
    tsum += v[j];
  }
  s[t] = tsum;
  __syncthreads();
  for (int off = 1; off < 256; off <<= 1) {
    int u = (t >= off) ? s[t - off] : 0;
    __syncthreads();
    s[t] += u;
    __syncthreads();
  }
  int run = bsum[blockIdx.x] + ((t > 0) ? s[t - 1] : 0);
#pragma unroll
  for (int j = 0; j < 8; ++j) {
    int i = base + j;
    if (i < nN) rowptr[i] = run;
    run += v[j];
  }
}

__global__ __launch_bounds__(256) void fill_kernel(const int* __restrict__ src,
    const int* __restrict__ dst, const int* __restrict__ rowptr,
    int* __restrict__ cursor, int* __restrict__ eidx, int nE) {
  int e = blockIdx.x * 256 + threadIdx.x;
  if (e < nE) {
    int d = dst[e];
    int p = atomicAdd(&cursor[d], 1);
    eidx[rowptr[d] + p] = src[e];
  }
}

// --- fp32 -> bf16 shadow copy (gather input) -------------------------------
__global__ __launch_bounds__(256) void cvt_x_kernel(const float* __restrict__ x,
    unsigned short* __restrict__ xh, int total8) {
  int idx = blockIdx.x * 256 + threadIdx.x;
  if (idx >= total8) return;
  float4 a = reinterpret_cast<const float4*>(x)[idx * 2];
  float4 b = reinterpret_cast<const float4*>(x)[idx * 2 + 1];
  u16x8 o;
  o[0] = (unsigned short)rne_bf16(a.x); o[1] = (unsigned short)rne_bf16(a.y);
  o[2] = (unsigned short)rne_bf16(a.z); o[3] = (unsigned short)rne_bf16(a.w);
  o[4] = (unsigned short)rne_bf16(b.x); o[5] = (unsigned short)rne_bf16(b.y);
  o[6] = (unsigned short)rne_bf16(b.z); o[7] = (unsigned short)rne_bf16(b.w);
  reinterpret_cast<u16x8*>(xh)[idx] = o;
}

// --- mean-aggregate via gather: 16 threads per dst node, bf16 input --------
__global__ __launch_bounds__(256) void gather_kernel(const unsigned short* __restrict__ xh,
    const int* __restrict__ rowptr, const int* __restrict__ eidx,
    float* __restrict__ agg, int nN) {
  int grp = (blockIdx.x * 256 + threadIdx.x) >> 4;
  int j = threadIdx.x & 15;  // 8 cols per lane
  if (grp >= nN) return;
  int lo = rowptr[grp], hi = rowptr[grp + 1];
  float acc[8] = {0.f, 0.f, 0.f, 0.f, 0.f, 0.f, 0.f, 0.f};
  int i = lo;
  for (; i + 1 < hi; i += 2) {
    int s0 = eidx[i], s1 = eidx[i + 1];
    u16x8 v0 = *reinterpret_cast<const u16x8*>(xh + (size_t)s0 * DIM + j * 8);
    u16x8 v1 = *reinterpret_cast<const u16x8*>(xh + (size_t)s1 * DIM + j * 8);
#pragma unroll
    for (int q = 0; q < 8; ++q) {
      acc[q] += bf16_hi_to_f32(v0[q]);
      acc[q] += bf16_hi_to_f32(v1[q]);
    }
  }
  if (i < hi) {
    int s0 = eidx[i];
    u16x8 v0 = *reinterpret_cast<const u16x8*>(xh + (size_t)s0 * DIM + j * 8);
#pragma unroll
    for (int q = 0; q < 8; ++q) acc[q] += bf16_hi_to_f32(v0[q]);
  }
  float invd = 1.0f / fmaxf((float)(hi - lo), 1.0f);
  float4 o0 = make_float4(acc[0] * invd, acc[1] * invd, acc[2] * invd, acc[3] * invd);
  float4 o1 = make_float4(acc[4] * invd, acc[5] * invd, acc[6] * invd, acc[7] * invd);
  float* p = agg + (size_t)grp * DIM + j * 8;
  *reinterpret_cast<float4*>(p) = o0;
  *reinterpret_cast<float4*>(p + 4) = o1;
}

// --- W prep ---------------------------------------------------------------
__global__ __launch_bounds__(256) void cvt_w_kernel(const float* __restrict__ Wl,
    const float* __restrict__ Wr, unsigned short* __restrict__ Wth,
    unsigned short* __restrict__ Wtl) {
  int idx = blockIdx.x * 256 + threadIdx.x;  // c*256 + k
  if (idx >= DIM * 256) return;
  int c = idx >> 8, k = idx & 255;
  float v = (k < DIM) ? Wl[(size_t)k * DIM + c] : Wr[(size_t)(k - DIM) * DIM + c];
  unsigned h = rne_bf16(v);
  float r = v - bf16_hi_to_f32(h);
  Wth[idx] = (unsigned short)h;
  Wtl[idx] = (unsigned short)rne_bf16(r);
}

// --- fused dual-GEMM via bf16 split-precision MFMA + LDS-staged W ----------
__global__ __launch_bounds__(256) void gemm_mfma_kernel(
    const float* __restrict__ A0, const float* __restrict__ A1,
    const unsigned short* __restrict__ Wth, const unsigned short* __restrict__ Wtl,
    const float* __restrict__ bias, float* __restrict__ h, int nN) {
  __shared__ unsigned short Wh_lds[DIM * 128];  // 32KB, [c][k] swizzled
  __shared__ unsigned short Wl_lds[DIM * 128];  // 32KB
  const int tid = threadIdx.x;
  const int lane = tid & 63;
  const int wave = tid >> 6;
  const int rbase = blockIdx.x * 128 + wave * 32;
  const int lrow = lane & 15;
  const int koff = (lane >> 4) * 8;

  f32x4 acc[2][8];
#pragma unroll
  for (int rt = 0; rt < 2; ++rt)
#pragma unroll
    for (int ct = 0; ct < 8; ++ct)
      acc[rt][ct] = (f32x4){0.f, 0.f, 0.f, 0.f};

  int r0 = rbase + lrow;      if (r0 > nN - 1) r0 = nN - 1;
  int r1 = rbase + 16 + lrow; if (r1 > nN - 1) r1 = nN - 1;

#pragma unroll
  for (int s = 0; s < 2; ++s) {
    __syncthreads();
#pragma unroll
    for (int i = 0; i < 8; ++i) {
      int idx = i * 256 + tid;   // 0..2047
      int c = idx >> 4;
      int kc = idx & 15;
      int lb = c * 256 + ((kc * 16) ^ ((c & 7) << 4));
      float4 hv = *reinterpret_cast<const float4*>(Wth + (size_t)c * 256 + s * 128 + kc * 8);
      float4 lv = *reinterpret_cast<const float4*>(Wtl + (size_t)c * 256 + s * 128 + kc * 8);
      *reinterpret_cast<float4*>(reinterpret_cast<char*>(Wh_lds) + lb) = hv;
      *reinterpret_cast<float4*>(reinterpret_cast<char*>(Wl_lds) + lb) = lv;
    }
    __syncthreads();

    const float* A = s ? A1 : A0;
    const float* a0p = A + (size_t)r0 * DIM;
    const float* a1p = A + (size_t)r1 * DIM;
#pragma unroll
    for (int ks = 0; ks < 4; ++ks) {
      int ka = ks * 32 + koff;
      s16x8 ah0, al0, ah1, al1;
      split_frag(a0p + ka, ah0, al0);
      split_frag(a1p + ka, ah1, al1);
#pragma unroll
      for (int ct = 0; ct < 8; ++ct) {
        int c = ct * 16 + lrow;
        int lb = c * 256 + ((ka * 2) ^ ((c & 7) << 4));
        s16x8 wh = *reinterpret_cast<const s16x8*>(reinterpret_cast<const char*>(Wh_lds) + lb);
        s16x8 wl = *reinterpret_cast<const s16x8*>(reinterpret_cast<const char*>(Wl_lds) + lb);
        acc[0][ct] = __builtin_amdgcn_mfma_f32_16x16x32_bf16(ah0, wh, acc[0][ct], 0, 0, 0);
        acc[0][ct] = __builtin_amdgcn_mfma_f32_16x16x32_bf16(ah0, wl, acc[0][ct], 0, 0, 0);
        acc[0][ct] = __builtin_amdgcn_mfma_f32_16x16x32_bf16(al0, wh, acc[0][ct], 0, 0, 0);
        acc[1][ct] = __builtin_amdgcn_mfma_f32_16x16x32_bf16(ah1, wh, acc[1][ct], 0, 0, 0);
        acc[1][ct] = __builtin_amdgcn_mfma_f32_16x16x32_bf16(ah1, wl, acc[1][ct], 0, 0, 0);
        acc[1][ct] = __builtin_amdgcn_mfma_f32_16x16x32_bf16(al1, wh, acc[1][ct], 0, 0, 0);
      }
    }
  }

#pragma unroll
  for (int ct = 0; ct < 8; ++ct) {
    int c = ct * 16 + lrow;
    float b = bias[c];
#pragma unroll
    for (int rt = 0; rt < 2; ++rt) {
      int rr = rbase + rt * 16 + (lane >> 4) * 4;
#pragma unroll
      for (int j = 0; j < 4; ++j) {
        int row = rr + j;
        if (row < nN) h[(size_t)row * DIM + c] = acc[rt][ct][j] + b;
      }
    }
  }
}

__global__ __launch_bounds__(256) void stats_kernel(const float* __restrict__ h,
                                                    float* __restrict__ sums, int nN) {
  __shared__ float s_s[256];
  __shared__ float s_q[256];
  int tid = threadIdx.x;
  int c = tid & 127;
  int rp = tid >> 7;
  float ls = 0.f, lq = 0.f;
  for (int r = blockIdx.x * 2 + rp; r < nN; r += gridDim.x * 2) {
    float v = h[(size_t)r * DIM + c];
    ls += v;
    lq += v * v;
  }
  s_s[tid] = ls;
  s_q[tid] = lq;
  __syncthreads();
  if (tid < 128) {
    atomicAdd(&sums[c], s_s[tid] + s_s[tid + 128]);
    atomicAdd(&sums[DIM + c], s_q[tid] + s_q[tid + 128]);
  }
}

// BN+ReLU: writes fp32 (GEMM root input) and bf16 shadow (gather input).
__global__ __launch_bounds__(256) void bn_relu_kernel(const float* __restrict__ h,
    const float* __restrict__ sums, const float* __restrict__ gamma,
    const float* __restrict__ beta, float* __restrict__ xout,
    unsigned short* __restrict__ xhout, int nN) {
  int idx = blockIdx.x * 256 + threadIdx.x;
  int total = nN * (DIM / 4);
  if (idx >= total) return;
  int c = (idx & 31) * 4;
  float invN = 1.0f / (float)nN;
  float4 hv = reinterpret_cast<const float4*>(h)[idx];
  const float* hp = reinterpret_cast<const float*>(&hv);
  float4 o;
  float* op = reinterpret_cast<float*>(&o);
  u16x4 oh;
#pragma unroll
  for (int j = 0; j < 4; ++j) {
    float mu = sums[c + j] * invN;
    float var = sums[DIM + c + j] * invN - mu * mu;
    float sc = gamma[c + j] * rsqrtf(var + EPS);
    float sh = beta[c + j] - mu * sc;
    op[j] = fmaxf(hp[j] * sc + sh, 0.0f);
    oh[j] = (unsigned short)rne_bf16(op[j]);
  }
  reinterpret_cast<float4*>(xout)[idx] = o;
  reinterpret_cast<u16x4*>(xhout)[idx] = oh;
}

// --- fused final BN+ReLU + segmented mean-pool ------------------------------
#define POOL_ROWS 32
__global__ __launch_bounds__(256) void pool_fused_kernel(const float* __restrict__ h,
    const float* __restrict__ sums, const float* __restrict__ gamma,
    const float* __restrict__ beta, const int* __restrict__ batch,
    float* __restrict__ outsum, int nN) {
  int c = threadIdx.x & 127;
  int rp = threadIdx.x >> 7;
  int r0 = blockIdx.x * POOL_ROWS;
  float invN = 1.0f / (float)nN;
  float mu = sums[c] * invN;
  float var = sums[DIM + c] * invN - mu * mu;
  float sc = gamma[c] * rsqrtf(var + EPS);
  float sh = beta[c] - mu * sc;
  int rend = min(r0 + POOL_ROWS, nN);
  float acc = 0.f;
  int cur = -1;
  for (int r = r0 + rp; r < rend; r += 2) {
    int g = batch[r];
    float v = fmaxf(h[(size_t)r * DIM + c] * sc + sh, 0.0f);
    if (g != cur) {
      if (cur >= 0) atomicAdd(&outsum[(size_t)cur * DIM + c], acc);
      cur = g; acc = 0.f;
    }
    acc += v;
  }
  if (cur >= 0) atomicAdd(&outsum[(size_t)cur * DIM + c], acc);
}

__global__ __launch_bounds__(256) void pool_div_kernel(const float* __restrict__ outsum,
    const int* __restrict__ batch, float* __restrict__ out, int nN, int nG) {
  int idx = blockIdx.x * 256 + threadIdx.x;  // g*128 + c
  if (idx >= nG * DIM) return;
  int g = idx >> 7;
  int lo = lower_bound_i(batch, nN, g);
  int hi = lower_bound_i(batch, nN, g + 1);
  float cnt = fmaxf((float)(hi - lo), 1.0f);
  out[idx] = outsum[idx] / cnt;
}

extern "C" void kernel_launch(void* const* d_in, const int* in_sizes, int n_in,
                              void* d_out, int out_size, void* d_ws, size_t ws_size,
                              hipStream_t stream) {
  const float* x     = (const float*)d_in[0];
  const int*   ei    = (const int*)d_in[1];
  const int*   batch = (const int*)d_in[2];
  const float* W_l   = (const float*)d_in[3];
  const float* b_l   = (const float*)d_in[4];
  const float* W_r   = (const float*)d_in[5];
  const float* gamma = (const float*)d_in[6];
  const float* beta  = (const float*)d_in[7];
  float* out = (float*)d_out;

  const int N = in_sizes[2];
  const int E = in_sizes[1] / 2;
  const int G = out_size / DIM;
  const int L = in_sizes[3] / (DIM * DIM);

  const int* src  = ei;
  const int* dstE = ei + E;

  const int nB = (N + SCAN_TILE - 1) / SCAN_TILE;

  // workspace layout
  char* wsb = (char*)d_ws;
  float* agg    = (float*)wsb;  wsb += (size_t)N * DIM * sizeof(float);
  float* h      = (float*)wsb;  wsb += (size_t)N * DIM * sizeof(float);
  float* xb     = (float*)wsb;  wsb += (size_t)N * DIM * sizeof(float);
  float* sums   = (float*)wsb;  wsb += 2 * DIM * sizeof(float);
  float* outsum = (float*)wsb;  wsb += (size_t)G * DIM * sizeof(float);
  int* cnt    = (int*)wsb;      wsb += (size_t)N * sizeof(int);
  int* rowptr = (int*)wsb;      wsb += (size_t)(N + 1) * sizeof(int);
  int* cursor = (int*)wsb;      wsb += (size_t)N * sizeof(int);
  int* bsum   = (int*)wsb;      wsb += (size_t)nB * sizeof(int);
  int* eidx   = (int*)wsb;      wsb += (size_t)E * sizeof(int);
  unsigned short* Wth = (unsigned short*)wsb; wsb += (size_t)DIM * 256 * sizeof(unsigned short);
  unsigned short* Wtl = (unsigned short*)wsb; wsb += (size_t)DIM * 256 * sizeof(unsigned short);
  unsigned short* xh  = (unsigned short*)wsb; wsb += (size_t)N * DIM * sizeof(unsigned short);

  // CSR build
  hipMemsetAsync(cnt, 0, (size_t)N * sizeof(int), stream);
  hipMemsetAsync(cursor, 0, (size_t)N * sizeof(int), stream);
  hist_kernel<<<(E + 255) / 256, 256, 0, stream>>>(dstE, cnt, E);
  scan1_kernel<<<nB, 256, 0, stream>>>(cnt, bsum, N);
  scan2_kernel<<<1, 64, 0, stream>>>(bsum, rowptr, nB, N);
  scan3_kernel<<<nB, 256, 0, stream>>>(cnt, bsum, rowptr, N);
  fill_kernel<<<(E + 255) / 256, 256, 0, stream>>>(src, dstE, rowptr, cursor, eidx, E);

  // bf16 shadow of layer-1 gather input
  cvt_x_kernel<<<(N * (DIM / 8) + 255) / 256, 256, 0, stream>>>(x, xh, N * (DIM / 8));

  const float* xin = x;
  for (int l = 0; l < L; ++l) {
    cvt_w_kernel<<<(DIM * 256 + 255) / 256, 256, 0, stream>>>(
        W_l + (size_t)l * DIM * DIM, W_r + (size_t)l * DIM * DIM, Wth, Wtl);
    gather_kernel<<<(N * 16 + 255) / 256, 256, 0, stream>>>(xh, rowptr, eidx, agg, N);
    gemm_mfma_kernel<<<(N + 127) / 128, 256, 0, stream>>>(agg, xin, Wth, Wtl,
        b_l + (size_t)l * DIM, h, N);
    hipMemsetAsync(sums, 0, 2 * DIM * sizeof(float), stream);
    stats_kernel<<<240, 256, 0, stream>>>(h, sums, N);
    if (l < L - 1) {
      bn_relu_kernel<<<(N * (DIM / 4) + 255) / 256, 256, 0, stream>>>(
          h, sums, gamma + (size_t)l * DIM, beta + (size_t)l * DIM, xb, xh, N);
      xin = xb;
    } else {
      hipMemsetAsync(outsum, 0, (size_t)G * DIM * sizeof(float), stream);
      pool_fused_kernel<<<(N + POOL_ROWS - 1) / POOL_ROWS, 256, 0, stream>>>(
          h, sums, gamma + (size_t)l * DIM, beta + (size_t)l * DIM, batch, outsum, N);
      pool_div_kernel<<<(G * DIM + 255) / 256, 256, 0, stream>>>(outsum, batch, out, N, G);
    }
  }
}

// Round 9
// 244.858 us; speedup vs baseline: 1.6798x; 1.2459x over previous
//
#include <hip/hip_runtime.h>

#define DIM 128
#define EPS 1e-5f
#define SCAN_TILE 2048  // 256 threads x 8 elements

typedef short s16x8 __attribute__((ext_vector_type(8)));
typedef unsigned short u16x8 __attribute__((ext_vector_type(8)));
typedef unsigned short u16x4 __attribute__((ext_vector_type(4)));
typedef float f32x4 __attribute__((ext_vector_type(4)));

__device__ __forceinline__ int lower_bound_i(const int* __restrict__ a, int n, int key) {
  int lo = 0, hi = n;
  while (lo < hi) {
    int mid = (lo + hi) >> 1;
    if (a[mid] < key) lo = mid + 1; else hi = mid;
  }
  return lo;
}

__device__ __forceinline__ unsigned rne_bf16(float f) {
  unsigned u = __builtin_bit_cast(unsigned, f);
  return (u + 0x7fffu + ((u >> 16) & 1u)) >> 16;
}
__device__ __forceinline__ float bf16_hi_to_f32(unsigned h) {
  return __builtin_bit_cast(float, h << 16);
}

// --- CSR build -------------------------------------------------------------
__global__ __launch_bounds__(256) void hist_kernel(const int* __restrict__ dst,
                                                   int* __restrict__ cnt, int nE) {
  int i = blockIdx.x * 256 + threadIdx.x;
  if (i < nE) atomicAdd(&cnt[dst[i]], 1);
}

__global__ __launch_bounds__(256) void scan1_kernel(const int* __restrict__ cnt,
                                                    int* __restrict__ bsum, int nN) {
  __shared__ int s[256];
  int t = threadIdx.x;
  int base = blockIdx.x * SCAN_TILE + t * 8;
  int sum = 0;
#pragma unroll
  for (int j = 0; j < 8; ++j) {
    int i = base + j;
    if (i < nN) sum += cnt[i];
  }
  s[t] = sum;
  __syncthreads();
  for (int off = 128; off > 0; off >>= 1) {
    if (t < off) s[t] += s[t + off];
    __syncthreads();
  }
  if (t == 0) bsum[blockIdx.x] = s[0];
}

__global__ __launch_bounds__(64) void scan2_kernel(int* __restrict__ bsum,
                                                   int* __restrict__ rowptr,
                                                   int nB, int nN) {
  if (threadIdx.x == 0) {
    int run = 0;
    for (int b = 0; b < nB; ++b) {
      int v = bsum[b];
      bsum[b] = run;
      run += v;
    }
    rowptr[nN] = run;
  }
}

__global__ __launch_bounds__(256) void scan3_kernel(const int* __restrict__ cnt,
                                                    const int* __restrict__ bsum,
                                                    int* __restrict__ rowptr, int nN) {
  __shared__ int s[256];
  int t = threadIdx.x;
  int base = blockIdx.x * SCAN_TILE + t * 8;
  int v[8];
  int tsum = 0;
#pragma unroll
  for (int j = 0; j < 8; ++j) {
    int i = base + j;
    v[j] = (i < nN) ? cnt[i] : 0;
    tsum += v[j];
  }
  s[t] = tsum;
  __syncthreads();
  for (int off = 1; off < 256; off <<= 1) {
    int u = (t >= off) ? s[t - off] : 0;
    __syncthreads();
    s[t] += u;
    __syncthreads();
  }
  int run = bsum[blockIdx.x] + ((t > 0) ? s[t - 1] : 0);
#pragma unroll
  for (int j = 0; j < 8; ++j) {
    int i = base + j;
    if (i < nN) rowptr[i] = run;
    run += v[j];
  }
}

__global__ __launch_bounds__(256) void fill_kernel(const int* __restrict__ src,
    const int* __restrict__ dst, const int* __restrict__ rowptr,
    int* __restrict__ cursor, int* __restrict__ eidx, int nE) {
  int e = blockIdx.x * 256 + threadIdx.x;
  if (e < nE) {
    int d = dst[e];
    int p = atomicAdd(&cursor[d], 1);
    eidx[rowptr[d] + p] = src[e];
  }
}

// --- fp32 -> bf16 shadow copy (layer-1 activations) ------------------------
__global__ __launch_bounds__(256) void cvt_x_kernel(const float* __restrict__ x,
    unsigned short* __restrict__ xh, int total8) {
  int idx = blockIdx.x * 256 + threadIdx.x;
  if (idx >= total8) return;
  float4 a = reinterpret_cast<const float4*>(x)[idx * 2];
  float4 b = reinterpret_cast<const float4*>(x)[idx * 2 + 1];
  u16x8 o;
  o[0] = (unsigned short)rne_bf16(a.x); o[1] = (unsigned short)rne_bf16(a.y);
  o[2] = (unsigned short)rne_bf16(a.z); o[3] = (unsigned short)rne_bf16(a.w);
  o[4] = (unsigned short)rne_bf16(b.x); o[5] = (unsigned short)rne_bf16(b.y);
  o[6] = (unsigned short)rne_bf16(b.z); o[7] = (unsigned short)rne_bf16(b.w);
  reinterpret_cast<u16x8*>(xh)[idx] = o;
}

// --- mean-aggregate via gather: 16 threads per dst node, bf16 in/out -------
__global__ __launch_bounds__(256) void gather_kernel(const unsigned short* __restrict__ xh,
    const int* __restrict__ rowptr, const int* __restrict__ eidx,
    unsigned short* __restrict__ aggh, int nN) {
  int grp = (blockIdx.x * 256 + threadIdx.x) >> 4;
  int j = threadIdx.x & 15;  // 8 cols per lane
  if (grp >= nN) return;
  int lo = rowptr[grp], hi = rowptr[grp + 1];
  float acc[8] = {0.f, 0.f, 0.f, 0.f, 0.f, 0.f, 0.f, 0.f};
  int i = lo;
  for (; i + 1 < hi; i += 2) {
    int s0 = eidx[i], s1 = eidx[i + 1];
    u16x8 v0 = *reinterpret_cast<const u16x8*>(xh + (size_t)s0 * DIM + j * 8);
    u16x8 v1 = *reinterpret_cast<const u16x8*>(xh + (size_t)s1 * DIM + j * 8);
#pragma unroll
    for (int q = 0; q < 8; ++q) {
      acc[q] += bf16_hi_to_f32(v0[q]);
      acc[q] += bf16_hi_to_f32(v1[q]);
    }
  }
  if (i < hi) {
    int s0 = eidx[i];
    u16x8 v0 = *reinterpret_cast<const u16x8*>(xh + (size_t)s0 * DIM + j * 8);
#pragma unroll
    for (int q = 0; q < 8; ++q) acc[q] += bf16_hi_to_f32(v0[q]);
  }
  float invd = 1.0f / fmaxf((float)(hi - lo), 1.0f);
  u16x8 o;
#pragma unroll
  for (int q = 0; q < 8; ++q) o[q] = (unsigned short)rne_bf16(acc[q] * invd);
  *reinterpret_cast<u16x8*>(aggh + (size_t)grp * DIM + j * 8) = o;
}

// --- W prep ---------------------------------------------------------------
__global__ __launch_bounds__(256) void cvt_w_kernel(const float* __restrict__ Wl,
    const float* __restrict__ Wr, unsigned short* __restrict__ Wth,
    unsigned short* __restrict__ Wtl) {
  int idx = blockIdx.x * 256 + threadIdx.x;  // c*256 + k
  if (idx >= DIM * 256) return;
  int c = idx >> 8, k = idx & 255;
  float v = (k < DIM) ? Wl[(size_t)k * DIM + c] : Wr[(size_t)(k - DIM) * DIM + c];
  unsigned h = rne_bf16(v);
  float r = v - bf16_hi_to_f32(h);
  Wth[idx] = (unsigned short)h;
  Wtl[idx] = (unsigned short)rne_bf16(r);
}

// --- fused dual-GEMM (bf16 A x split-W MFMA) + BN-stats epilogue -----------
// Block: 256 threads = 4 waves; wave tile 32 rows x 128 cols.
// A operands are bf16 (agg, x); W is hi+lo bf16 staged in LDS (swizzled).
// Epilogue: per-block column sum/sumsq -> LDS -> one global atomic per col.
__global__ __launch_bounds__(256) void gemm_mfma_kernel(
    const unsigned short* __restrict__ A0h, const unsigned short* __restrict__ A1h,
    const unsigned short* __restrict__ Wth, const unsigned short* __restrict__ Wtl,
    const float* __restrict__ bias, float* __restrict__ h,
    float* __restrict__ sums, int nN) {
  __shared__ unsigned short Wh_lds[DIM * 128];  // 32KB, [c][k] swizzled
  __shared__ unsigned short Wl_lds[DIM * 128];  // 32KB
  __shared__ float s_sum[DIM];
  __shared__ float s_sq[DIM];
  const int tid = threadIdx.x;
  const int lane = tid & 63;
  const int wave = tid >> 6;
  const int rbase = blockIdx.x * 128 + wave * 32;
  const int lrow = lane & 15;
  const int koff = (lane >> 4) * 8;

  f32x4 acc[2][8];
#pragma unroll
  for (int rt = 0; rt < 2; ++rt)
#pragma unroll
    for (int ct = 0; ct < 8; ++ct)
      acc[rt][ct] = (f32x4){0.f, 0.f, 0.f, 0.f};

  int r0 = rbase + lrow;      if (r0 > nN - 1) r0 = nN - 1;
  int r1 = rbase + 16 + lrow; if (r1 > nN - 1) r1 = nN - 1;

#pragma unroll
  for (int s = 0; s < 2; ++s) {
    __syncthreads();  // protect prior phase's LDS reads before overwrite
#pragma unroll
    for (int i = 0; i < 8; ++i) {
      int idx = i * 256 + tid;   // 0..2047
      int c = idx >> 4;
      int kc = idx & 15;
      int lb = c * 256 + ((kc * 16) ^ ((c & 7) << 4));
      float4 hv = *reinterpret_cast<const float4*>(Wth + (size_t)c * 256 + s * 128 + kc * 8);
      float4 lv = *reinterpret_cast<const float4*>(Wtl + (size_t)c * 256 + s * 128 + kc * 8);
      *reinterpret_cast<float4*>(reinterpret_cast<char*>(Wh_lds) + lb) = hv;
      *reinterpret_cast<float4*>(reinterpret_cast<char*>(Wl_lds) + lb) = lv;
    }
    __syncthreads();

    const unsigned short* A = s ? A1h : A0h;
#pragma unroll
    for (int ks = 0; ks < 4; ++ks) {
      int ka = ks * 32 + koff;
      s16x8 a0 = *reinterpret_cast<const s16x8*>(A + (size_t)r0 * DIM + ka);
      s16x8 a1 = *reinterpret_cast<const s16x8*>(A + (size_t)r1 * DIM + ka);
#pragma unroll
      for (int ct = 0; ct < 8; ++ct) {
        int c = ct * 16 + lrow;
        int lb = c * 256 + ((ka * 2) ^ ((c & 7) << 4));
        s16x8 wh = *reinterpret_cast<const s16x8*>(reinterpret_cast<const char*>(Wh_lds) + lb);
        s16x8 wl = *reinterpret_cast<const s16x8*>(reinterpret_cast<const char*>(Wl_lds) + lb);
        acc[0][ct] = __builtin_amdgcn_mfma_f32_16x16x32_bf16(a0, wh, acc[0][ct], 0, 0, 0);
        acc[0][ct] = __builtin_amdgcn_mfma_f32_16x16x32_bf16(a0, wl, acc[0][ct], 0, 0, 0);
        acc[1][ct] = __builtin_amdgcn_mfma_f32_16x16x32_bf16(a1, wh, acc[1][ct], 0, 0, 0);
        acc[1][ct] = __builtin_amdgcn_mfma_f32_16x16x32_bf16(a1, wl, acc[1][ct], 0, 0, 0);
      }
    }
  }

  // epilogue: store h and accumulate BN stats
  if (tid < DIM) { s_sum[tid] = 0.f; s_sq[tid] = 0.f; }
  __syncthreads();
  float csum[8], csq[8];
#pragma unroll
  for (int ct = 0; ct < 8; ++ct) { csum[ct] = 0.f; csq[ct] = 0.f; }
#pragma unroll
  for (int ct = 0; ct < 8; ++ct) {
    int c = ct * 16 + lrow;
    float b = bias[c];
#pragma unroll
    for (int rt = 0; rt < 2; ++rt) {
      int rr = rbase + rt * 16 + (lane >> 4) * 4;
#pragma unroll
      for (int j = 0; j < 4; ++j) {
        int row = rr + j;
        if (row < nN) {
          float v = acc[rt][ct][j] + b;
          h[(size_t)row * DIM + c] = v;
          csum[ct] += v;
          csq[ct] += v * v;
        }
      }
    }
  }
#pragma unroll
  for (int ct = 0; ct < 8; ++ct) {
    csum[ct] += __shfl_xor(csum[ct], 16);
    csum[ct] += __shfl_xor(csum[ct], 32);
    csq[ct]  += __shfl_xor(csq[ct], 16);
    csq[ct]  += __shfl_xor(csq[ct], 32);
  }
  if (lane < 16) {
#pragma unroll
    for (int ct = 0; ct < 8; ++ct) {
      atomicAdd(&s_sum[ct * 16 + lane], csum[ct]);
      atomicAdd(&s_sq[ct * 16 + lane], csq[ct]);
    }
  }
  __syncthreads();
  if (tid < DIM) {
    atomicAdd(&sums[tid], s_sum[tid]);
    atomicAdd(&sums[DIM + tid], s_sq[tid]);
  }
}

// BN+ReLU: writes only the bf16 activation buffer for the next layer.
__global__ __launch_bounds__(256) void bn_relu_kernel(const float* __restrict__ h,
    const float* __restrict__ sums, const float* __restrict__ gamma,
    const float* __restrict__ beta, unsigned short* __restrict__ xhout, int nN) {
  int idx = blockIdx.x * 256 + threadIdx.x;
  int total = nN * (DIM / 4);
  if (idx >= total) return;
  int c = (idx & 31) * 4;
  float invN = 1.0f / (float)nN;
  float4 hv = reinterpret_cast<const float4*>(h)[idx];
  const float* hp = reinterpret_cast<const float*>(&hv);
  u16x4 oh;
#pragma unroll
  for (int j = 0; j < 4; ++j) {
    float mu = sums[c + j] * invN;
    float var = sums[DIM + c + j] * invN - mu * mu;
    float sc = gamma[c + j] * rsqrtf(var + EPS);
    float sh = beta[c + j] - mu * sc;
    float v = fmaxf(hp[j] * sc + sh, 0.0f);
    oh[j] = (unsigned short)rne_bf16(v);
  }
  reinterpret_cast<u16x4*>(xhout)[idx] = oh;
}

// --- fused final BN+ReLU + segmented mean-pool ------------------------------
#define POOL_ROWS 32
__global__ __launch_bounds__(256) void pool_fused_kernel(const float* __restrict__ h,
    const float* __restrict__ sums, const float* __restrict__ gamma,
    const float* __restrict__ beta, const int* __restrict__ batch,
    float* __restrict__ outsum, int nN) {
  int c = threadIdx.x & 127;
  int rp = threadIdx.x >> 7;
  int r0 = blockIdx.x * POOL_ROWS;
  float invN = 1.0f / (float)nN;
  float mu = sums[c] * invN;
  float var = sums[DIM + c] * invN - mu * mu;
  float sc = gamma[c] * rsqrtf(var + EPS);
  float sh = beta[c] - mu * sc;
  int rend = min(r0 + POOL_ROWS, nN);
  float acc = 0.f;
  int cur = -1;
  for (int r = r0 + rp; r < rend; r += 2) {
    int g = batch[r];
    float v = fmaxf(h[(size_t)r * DIM + c] * sc + sh, 0.0f);
    if (g != cur) {
      if (cur >= 0) atomicAdd(&outsum[(size_t)cur * DIM + c], acc);
      cur = g; acc = 0.f;
    }
    acc += v;
  }
  if (cur >= 0) atomicAdd(&outsum[(size_t)cur * DIM + c], acc);
}

__global__ __launch_bounds__(256) void pool_div_kernel(const float* __restrict__ outsum,
    const int* __restrict__ batch, float* __restrict__ out, int nN, int nG) {
  int idx = blockIdx.x * 256 + threadIdx.x;  // g*128 + c
  if (idx >= nG * DIM) return;
  int g = idx >> 7;
  int lo = lower_bound_i(batch, nN, g);
  int hi = lower_bound_i(batch, nN, g + 1);
  float cnt = fmaxf((float)(hi - lo), 1.0f);
  out[idx] = outsum[idx] / cnt;
}

extern "C" void kernel_launch(void* const* d_in, const int* in_sizes, int n_in,
                              void* d_out, int out_size, void* d_ws, size_t ws_size,
                              hipStream_t stream) {
  const float* x     = (const float*)d_in[0];
  const int*   ei    = (const int*)d_in[1];
  const int*   batch = (const int*)d_in[2];
  const float* W_l   = (const float*)d_in[3];
  const float* b_l   = (const float*)d_in[4];
  const float* W_r   = (const float*)d_in[5];
  const float* gamma = (const float*)d_in[6];
  const float* beta  = (const float*)d_in[7];
  float* out = (float*)d_out;

  const int N = in_sizes[2];
  const int E = in_sizes[1] / 2;
  const int G = out_size / DIM;
  const int L = in_sizes[3] / (DIM * DIM);

  const int* src  = ei;
  const int* dstE = ei + E;

  const int nB = (N + SCAN_TILE - 1) / SCAN_TILE;

  // workspace layout
  char* wsb = (char*)d_ws;
  float* h      = (float*)wsb;  wsb += (size_t)N * DIM * sizeof(float);
  float* sums   = (float*)wsb;  wsb += 2 * DIM * sizeof(float);
  float* outsum = (float*)wsb;  wsb += (size_t)G * DIM * sizeof(float);
  int* cnt    = (int*)wsb;      wsb += (size_t)N * sizeof(int);
  int* rowptr = (int*)wsb;      wsb += (size_t)(N + 1) * sizeof(int);
  int* cursor = (int*)wsb;      wsb += (size_t)N * sizeof(int);
  int* bsum   = (int*)wsb;      wsb += (size_t)nB * sizeof(int);
  int* eidx   = (int*)wsb;      wsb += (size_t)E * sizeof(int);
  unsigned short* Wth  = (unsigned short*)wsb; wsb += (size_t)DIM * 256 * sizeof(unsigned short);
  unsigned short* Wtl  = (unsigned short*)wsb; wsb += (size_t)DIM * 256 * sizeof(unsigned short);
  unsigned short* xh   = (unsigned short*)wsb; wsb += (size_t)N * DIM * sizeof(unsigned short);
  unsigned short* aggh = (unsigned short*)wsb; wsb += (size_t)N * DIM * sizeof(unsigned short);

  // CSR build
  hipMemsetAsync(cnt, 0, (size_t)N * sizeof(int), stream);
  hipMemsetAsync(cursor, 0, (size_t)N * sizeof(int), stream);
  hist_kernel<<<(E + 255) / 256, 256, 0, stream>>>(dstE, cnt, E);
  scan1_kernel<<<nB, 256, 0, stream>>>(cnt, bsum, N);
  scan2_kernel<<<1, 64, 0, stream>>>(bsum, rowptr, nB, N);
  scan3_kernel<<<nB, 256, 0, stream>>>(cnt, bsum, rowptr, N);
  fill_kernel<<<(E + 255) / 256, 256, 0, stream>>>(src, dstE, rowptr, cursor, eidx, E);

  // bf16 shadow of layer-1 activations
  cvt_x_kernel<<<(N * (DIM / 8) + 255) / 256, 256, 0, stream>>>(x, xh, N * (DIM / 8));

  for (int l = 0; l < L; ++l) {
    cvt_w_kernel<<<(DIM * 256 + 255) / 256, 256, 0, stream>>>(
        W_l + (size_t)l * DIM * DIM, W_r + (size_t)l * DIM * DIM, Wth, Wtl);
    gather_kernel<<<(N * 16 + 255) / 256, 256, 0, stream>>>(xh, rowptr, eidx, aggh, N);
    hipMemsetAsync(sums, 0, 2 * DIM * sizeof(float), stream);
    gemm_mfma_kernel<<<(N + 127) / 128, 256, 0, stream>>>(aggh, xh, Wth, Wtl,
        b_l + (size_t)l * DIM, h, sums, N);
    if (l < L - 1) {
      bn_relu_kernel<<<(N * (DIM / 4) + 255) / 256, 256, 0, stream>>>(
          h, sums, gamma + (size_t)l * DIM, beta + (size_t)l * DIM, xh, N);
    } else {
      hipMemsetAsync(outsum, 0, (size_t)G * DIM * sizeof(float), stream);
      pool_fused_kernel<<<(N + POOL_ROWS - 1) / POOL_ROWS, 256, 0, stream>>>(
          h, sums, gamma + (size_t)l * DIM, beta + (size_t)l * DIM, batch, outsum, N);
      pool_div_kernel<<<(G * DIM + 255) / 256, 256, 0, stream>>>(outsum, batch, out, N, G);
    }
  }
}

// Round 10
// 217.991 us; speedup vs baseline: 1.8868x; 1.1232x over previous
//
#include <hip/hip_runtime.h>

#define DIM 128
#define EPS 1e-5f
#define SCAN_TILE 2048  // 256 threads x 8 elements

typedef short s16x8 __attribute__((ext_vector_type(8)));
typedef unsigned short u16x8 __attribute__((ext_vector_type(8)));
typedef float f32x4 __attribute__((ext_vector_type(4)));

__device__ __forceinline__ int lower_bound_i(const int* __restrict__ a, int n, int key) {
  int lo = 0, hi = n;
  while (lo < hi) {
    int mid = (lo + hi) >> 1;
    if (a[mid] < key) lo = mid + 1; else hi = mid;
  }
  return lo;
}

__device__ __forceinline__ unsigned rne_bf16(float f) {
  unsigned u = __builtin_bit_cast(unsigned, f);
  return (u + 0x7fffu + ((u >> 16) & 1u)) >> 16;
}
__device__ __forceinline__ float bf16_hi_to_f32(unsigned h) {
  return __builtin_bit_cast(float, h << 16);
}

// --- one kernel replaces all memsets ---------------------------------------
__global__ __launch_bounds__(256) void init_zero_kernel(float4* __restrict__ p, int n4) {
  int i = blockIdx.x * 256 + threadIdx.x;
  if (i < n4) p[i] = make_float4(0.f, 0.f, 0.f, 0.f);
}

// --- histogram + bf16 shadow of layer-1 activations (merged) ---------------
__global__ __launch_bounds__(256) void hist_cvt_kernel(const int* __restrict__ dst,
    int* __restrict__ cnt, const float* __restrict__ x,
    unsigned short* __restrict__ xh, int nE, int total8) {
  int i = blockIdx.x * 256 + threadIdx.x;
  if (i < nE) atomicAdd(&cnt[dst[i]], 1);
  if (i < total8) {
    float4 a = reinterpret_cast<const float4*>(x)[i * 2];
    float4 b = reinterpret_cast<const float4*>(x)[i * 2 + 1];
    u16x8 o;
    o[0] = (unsigned short)rne_bf16(a.x); o[1] = (unsigned short)rne_bf16(a.y);
    o[2] = (unsigned short)rne_bf16(a.z); o[3] = (unsigned short)rne_bf16(a.w);
    o[4] = (unsigned short)rne_bf16(b.x); o[5] = (unsigned short)rne_bf16(b.y);
    o[6] = (unsigned short)rne_bf16(b.z); o[7] = (unsigned short)rne_bf16(b.w);
    reinterpret_cast<u16x8*>(xh)[i] = o;
  }
}

// --- 3-phase scan ----------------------------------------------------------
__global__ __launch_bounds__(256) void scan1_kernel(const int* __restrict__ cnt,
                                                    int* __restrict__ bsum, int nN) {
  __shared__ int s[256];
  int t = threadIdx.x;
  int base = blockIdx.x * SCAN_TILE + t * 8;
  int sum = 0;
#pragma unroll
  for (int j = 0; j < 8; ++j) {
    int i = base + j;
    if (i < nN) sum += cnt[i];
  }
  s[t] = sum;
  __syncthreads();
  for (int off = 128; off > 0; off >>= 1) {
    if (t < off) s[t] += s[t + off];
    __syncthreads();
  }
  if (t == 0) bsum[blockIdx.x] = s[0];
}

__global__ __launch_bounds__(64) void scan2_kernel(int* __restrict__ bsum,
                                                   int* __restrict__ rowptr,
                                                   int nB, int nN) {
  if (threadIdx.x == 0) {
    int run = 0;
    for (int b = 0; b < nB; ++b) {
      int v = bsum[b];
      bsum[b] = run;
      run += v;
    }
    rowptr[nN] = run;
  }
}

__global__ __launch_bounds__(256) void scan3_kernel(const int* __restrict__ cnt,
                                                    const int* __restrict__ bsum,
                                                    int* __restrict__ rowptr, int nN) {
  __shared__ int s[256];
  int t = threadIdx.x;
  int base = blockIdx.x * SCAN_TILE + t * 8;
  int v[8];
  int tsum = 0;
#pragma unroll
  for (int j = 0; j < 8; ++j) {
    int i = base + j;
    v[j] = (i < nN) ? cnt[i] : 0;
    tsum += v[j];
  }
  s[t] = tsum;
  __syncthreads();
  for (int off = 1; off < 256; off <<= 1) {
    int u = (t >= off) ? s[t - off] : 0;
    __syncthreads();
    s[t] += u;
    __syncthreads();
  }
  int run = bsum[blockIdx.x] + ((t > 0) ? s[t - 1] : 0);
#pragma unroll
  for (int j = 0; j < 8; ++j) {
    int i = base + j;
    if (i < nN) rowptr[i] = run;
    run += v[j];
  }
}

__global__ __launch_bounds__(256) void fill_kernel(const int* __restrict__ src,
    const int* __restrict__ dst, const int* __restrict__ rowptr,
    int* __restrict__ cursor, int* __restrict__ eidx, int nE) {
  int e = blockIdx.x * 256 + threadIdx.x;
  if (e < nE) {
    int d = dst[e];
    int p = atomicAdd(&cursor[d], 1);
    eidx[rowptr[d] + p] = src[e];
  }
}

// --- mean-aggregate via gather: 16 threads per dst node, bf16 in/out -------
__global__ __launch_bounds__(256) void gather_kernel(const unsigned short* __restrict__ xh,
    const int* __restrict__ rowptr, const int* __restrict__ eidx,
    unsigned short* __restrict__ aggh, int nN) {
  int grp = (blockIdx.x * 256 + threadIdx.x) >> 4;
  int j = threadIdx.x & 15;  // 8 cols per lane
  if (grp >= nN) return;
  int lo = rowptr[grp], hi = rowptr[grp + 1];
  float acc[8] = {0.f, 0.f, 0.f, 0.f, 0.f, 0.f, 0.f, 0.f};
  int i = lo;
  for (; i + 1 < hi; i += 2) {
    int s0 = eidx[i], s1 = eidx[i + 1];
    u16x8 v0 = *reinterpret_cast<const u16x8*>(xh + (size_t)s0 * DIM + j * 8);
    u16x8 v1 = *reinterpret_cast<const u16x8*>(xh + (size_t)s1 * DIM + j * 8);
#pragma unroll
    for (int q = 0; q < 8; ++q) {
      acc[q] += bf16_hi_to_f32(v0[q]);
      acc[q] += bf16_hi_to_f32(v1[q]);
    }
  }
  if (i < hi) {
    int s0 = eidx[i];
    u16x8 v0 = *reinterpret_cast<const u16x8*>(xh + (size_t)s0 * DIM + j * 8);
#pragma unroll
    for (int q = 0; q < 8; ++q) acc[q] += bf16_hi_to_f32(v0[q]);
  }
  float invd = 1.0f / fmaxf((float)(hi - lo), 1.0f);
  u16x8 o;
#pragma unroll
  for (int q = 0; q < 8; ++q) o[q] = (unsigned short)rne_bf16(acc[q] * invd);
  *reinterpret_cast<u16x8*>(aggh + (size_t)grp * DIM + j * 8) = o;
}

// --- W prep: both layers in one launch -------------------------------------
__global__ __launch_bounds__(256) void cvt_w_kernel(const float* __restrict__ W_l,
    const float* __restrict__ W_r, unsigned short* __restrict__ Wth,
    unsigned short* __restrict__ Wtl, int nL) {
  int idx = blockIdx.x * 256 + threadIdx.x;  // l*DIM*256 + c*256 + k
  if (idx >= nL * DIM * 256) return;
  int l = idx / (DIM * 256);
  int rem = idx - l * DIM * 256;
  int c = rem >> 8, k = rem & 255;
  const float* Wl = W_l + (size_t)l * DIM * DIM;
  const float* Wr = W_r + (size_t)l * DIM * DIM;
  float v = (k < DIM) ? Wl[(size_t)k * DIM + c] : Wr[(size_t)(k - DIM) * DIM + c];
  unsigned h = rne_bf16(v);
  float r = v - bf16_hi_to_f32(h);
  Wth[idx] = (unsigned short)h;
  Wtl[idx] = (unsigned short)rne_bf16(r);
}

// --- fused dual-GEMM (bf16 A x split-W MFMA) + BN-stats epilogue -----------
// h stored bf16; stats accumulated from fp32 registers before rounding.
__global__ __launch_bounds__(256) void gemm_mfma_kernel(
    const unsigned short* __restrict__ A0h, const unsigned short* __restrict__ A1h,
    const unsigned short* __restrict__ Wth, const unsigned short* __restrict__ Wtl,
    const float* __restrict__ bias, unsigned short* __restrict__ h,
    float* __restrict__ sums, int nN) {
  __shared__ unsigned short Wh_lds[DIM * 128];  // 32KB, [c][k] swizzled
  __shared__ unsigned short Wl_lds[DIM * 128];  // 32KB
  __shared__ float s_sum[DIM];
  __shared__ float s_sq[DIM];
  const int tid = threadIdx.x;
  const int lane = tid & 63;
  const int wave = tid >> 6;
  const int rbase = blockIdx.x * 128 + wave * 32;
  const int lrow = lane & 15;
  const int koff = (lane >> 4) * 8;

  f32x4 acc[2][8];
#pragma unroll
  for (int rt = 0; rt < 2; ++rt)
#pragma unroll
    for (int ct = 0; ct < 8; ++ct)
      acc[rt][ct] = (f32x4){0.f, 0.f, 0.f, 0.f};

  int r0 = rbase + lrow;      if (r0 > nN - 1) r0 = nN - 1;
  int r1 = rbase + 16 + lrow; if (r1 > nN - 1) r1 = nN - 1;

#pragma unroll
  for (int s = 0; s < 2; ++s) {
    __syncthreads();
#pragma unroll
    for (int i = 0; i < 8; ++i) {
      int idx = i * 256 + tid;   // 0..2047
      int c = idx >> 4;
      int kc = idx & 15;
      int lb = c * 256 + ((kc * 16) ^ ((c & 7) << 4));
      float4 hv = *reinterpret_cast<const float4*>(Wth + (size_t)c * 256 + s * 128 + kc * 8);
      float4 lv = *reinterpret_cast<const float4*>(Wtl + (size_t)c * 256 + s * 128 + kc * 8);
      *reinterpret_cast<float4*>(reinterpret_cast<char*>(Wh_lds) + lb) = hv;
      *reinterpret_cast<float4*>(reinterpret_cast<char*>(Wl_lds) + lb) = lv;
    }
    __syncthreads();

    const unsigned short* A = s ? A1h : A0h;
#pragma unroll
    for (int ks = 0; ks < 4; ++ks) {
      int ka = ks * 32 + koff;
      s16x8 a0 = *reinterpret_cast<const s16x8*>(A + (size_t)r0 * DIM + ka);
      s16x8 a1 = *reinterpret_cast<const s16x8*>(A + (size_t)r1 * DIM + ka);
#pragma unroll
      for (int ct = 0; ct < 8; ++ct) {
        int c = ct * 16 + lrow;
        int lb = c * 256 + ((ka * 2) ^ ((c & 7) << 4));
        s16x8 wh = *reinterpret_cast<const s16x8*>(reinterpret_cast<const char*>(Wh_lds) + lb);
        s16x8 wl = *reinterpret_cast<const s16x8*>(reinterpret_cast<const char*>(Wl_lds) + lb);
        acc[0][ct] = __builtin_amdgcn_mfma_f32_16x16x32_bf16(a0, wh, acc[0][ct], 0, 0, 0);
        acc[0][ct] = __builtin_amdgcn_mfma_f32_16x16x32_bf16(a0, wl, acc[0][ct], 0, 0, 0);
        acc[1][ct] = __builtin_amdgcn_mfma_f32_16x16x32_bf16(a1, wh, acc[1][ct], 0, 0, 0);
        acc[1][ct] = __builtin_amdgcn_mfma_f32_16x16x32_bf16(a1, wl, acc[1][ct], 0, 0, 0);
      }
    }
  }

  // epilogue: store h (bf16) and accumulate BN stats from fp32 values
  if (tid < DIM) { s_sum[tid] = 0.f; s_sq[tid] = 0.f; }
  __syncthreads();
  float csum[8], csq[8];
#pragma unroll
  for (int ct = 0; ct < 8; ++ct) { csum[ct] = 0.f; csq[ct] = 0.f; }
#pragma unroll
  for (int ct = 0; ct < 8; ++ct) {
    int c = ct * 16 + lrow;
    float b = bias[c];
#pragma unroll
    for (int rt = 0; rt < 2; ++rt) {
      int rr = rbase + rt * 16 + (lane >> 4) * 4;
#pragma unroll
      for (int j = 0; j < 4; ++j) {
        int row = rr + j;
        if (row < nN) {
          float v = acc[rt][ct][j] + b;
          h[(size_t)row * DIM + c] = (unsigned short)rne_bf16(v);
          csum[ct] += v;
          csq[ct] += v * v;
        }
      }
    }
  }
#pragma unroll
  for (int ct = 0; ct < 8; ++ct) {
    csum[ct] += __shfl_xor(csum[ct], 16);
    csum[ct] += __shfl_xor(csum[ct], 32);
    csq[ct]  += __shfl_xor(csq[ct], 16);
    csq[ct]  += __shfl_xor(csq[ct], 32);
  }
  if (lane < 16) {
#pragma unroll
    for (int ct = 0; ct < 8; ++ct) {
      atomicAdd(&s_sum[ct * 16 + lane], csum[ct]);
      atomicAdd(&s_sq[ct * 16 + lane], csq[ct]);
    }
  }
  __syncthreads();
  if (tid < DIM) {
    atomicAdd(&sums[tid], s_sum[tid]);
    atomicAdd(&sums[DIM + tid], s_sq[tid]);
  }
}

// BN+ReLU: bf16 h in, bf16 activations out (8 elems/thread).
__global__ __launch_bounds__(256) void bn_relu_kernel(const unsigned short* __restrict__ h,
    const float* __restrict__ sums, const float* __restrict__ gamma,
    const float* __restrict__ beta, unsigned short* __restrict__ xhout, int nN) {
  int idx = blockIdx.x * 256 + threadIdx.x;
  int total = nN * (DIM / 8);
  if (idx >= total) return;
  int c = (idx & 15) * 8;
  float invN = 1.0f / (float)nN;
  u16x8 hv = reinterpret_cast<const u16x8*>(h)[idx];
  u16x8 oh;
#pragma unroll
  for (int j = 0; j < 8; ++j) {
    float mu = sums[c + j] * invN;
    float var = sums[DIM + c + j] * invN - mu * mu;
    float sc = gamma[c + j] * rsqrtf(var + EPS);
    float sh = beta[c + j] - mu * sc;
    float v = fmaxf(bf16_hi_to_f32(hv[j]) * sc + sh, 0.0f);
    oh[j] = (unsigned short)rne_bf16(v);
  }
  reinterpret_cast<u16x8*>(xhout)[idx] = oh;
}

// --- fused final BN+ReLU + segmented mean-pool ------------------------------
#define POOL_ROWS 32
__global__ __launch_bounds__(256) void pool_fused_kernel(const unsigned short* __restrict__ h,
    const float* __restrict__ sums, const float* __restrict__ gamma,
    const float* __restrict__ beta, const int* __restrict__ batch,
    float* __restrict__ outsum, int nN) {
  int c = threadIdx.x & 127;
  int rp = threadIdx.x >> 7;
  int r0 = blockIdx.x * POOL_ROWS;
  float invN = 1.0f / (float)nN;
  float mu = sums[c] * invN;
  float var = sums[DIM + c] * invN - mu * mu;
  float sc = gamma[c] * rsqrtf(var + EPS);
  float sh = beta[c] - mu * sc;
  int rend = min(r0 + POOL_ROWS, nN);
  float acc = 0.f;
  int cur = -1;
  for (int r = r0 + rp; r < rend; r += 2) {
    int g = batch[r];
    float v = fmaxf(bf16_hi_to_f32(h[(size_t)r * DIM + c]) * sc + sh, 0.0f);
    if (g != cur) {
      if (cur >= 0) atomicAdd(&outsum[(size_t)cur * DIM + c], acc);
      cur = g; acc = 0.f;
    }
    acc += v;
  }
  if (cur >= 0) atomicAdd(&outsum[(size_t)cur * DIM + c], acc);
}

__global__ __launch_bounds__(256) void pool_div_kernel(const float* __restrict__ outsum,
    const int* __restrict__ batch, float* __restrict__ out, int nN, int nG) {
  int idx = blockIdx.x * 256 + threadIdx.x;  // g*128 + c
  if (idx >= nG * DIM) return;
  int g = idx >> 7;
  int lo = lower_bound_i(batch, nN, g);
  int hi = lower_bound_i(batch, nN, g + 1);
  float cnt = fmaxf((float)(hi - lo), 1.0f);
  out[idx] = outsum[idx] / cnt;
}

extern "C" void kernel_launch(void* const* d_in, const int* in_sizes, int n_in,
                              void* d_out, int out_size, void* d_ws, size_t ws_size,
                              hipStream_t stream) {
  const float* x     = (const float*)d_in[0];
  const int*   ei    = (const int*)d_in[1];
  const int*   batch = (const int*)d_in[2];
  const float* W_l   = (const float*)d_in[3];
  const float* b_l   = (const float*)d_in[4];
  const float* W_r   = (const float*)d_in[5];
  const float* gamma = (const float*)d_in[6];
  const float* beta  = (const float*)d_in[7];
  float* out = (float*)d_out;

  const int N = in_sizes[2];
  const int E = in_sizes[1] / 2;
  const int G = out_size / DIM;
  const int L = in_sizes[3] / (DIM * DIM);

  const int* src  = ei;
  const int* dstE = ei + E;

  const int nB = (N + SCAN_TILE - 1) / SCAN_TILE;

  // workspace layout (zeroed region contiguous: cnt|cursor|sums(L)|outsum)
  char* wsb = (char*)d_ws;
  unsigned short* h    = (unsigned short*)wsb; wsb += (size_t)N * DIM * sizeof(unsigned short);
  unsigned short* xh   = (unsigned short*)wsb; wsb += (size_t)N * DIM * sizeof(unsigned short);
  unsigned short* aggh = (unsigned short*)wsb; wsb += (size_t)N * DIM * sizeof(unsigned short);
  unsigned short* Wth  = (unsigned short*)wsb; wsb += (size_t)L * DIM * 256 * sizeof(unsigned short);
  unsigned short* Wtl  = (unsigned short*)wsb; wsb += (size_t)L * DIM * 256 * sizeof(unsigned short);
  char* zbase = wsb;
  int* cnt      = (int*)wsb;    wsb += (size_t)N * sizeof(int);
  int* cursor   = (int*)wsb;    wsb += (size_t)N * sizeof(int);
  float* sums   = (float*)wsb;  wsb += (size_t)L * 2 * DIM * sizeof(float);
  float* outsum = (float*)wsb;  wsb += (size_t)G * DIM * sizeof(float);
  int zbytes = (int)((char*)wsb - zbase);
  int* rowptr = (int*)wsb;      wsb += (size_t)(N + 1) * sizeof(int);
  int* bsum   = (int*)wsb;      wsb += (size_t)nB * sizeof(int);
  int* eidx   = (int*)wsb;      wsb += (size_t)E * sizeof(int);

  // 1. zero everything that needs zeroing (one node)
  int n4 = zbytes / 16;
  init_zero_kernel<<<(n4 + 255) / 256, 256, 0, stream>>>((float4*)zbase, n4);
  // 2. histogram + bf16 shadow of x (one node)
  int total8 = N * (DIM / 8);
  int histcvt_n = max(E, total8);
  hist_cvt_kernel<<<(histcvt_n + 255) / 256, 256, 0, stream>>>(dstE, cnt, x, xh, E, total8);
  // 3-5. scan
  scan1_kernel<<<nB, 256, 0, stream>>>(cnt, bsum, N);
  scan2_kernel<<<1, 64, 0, stream>>>(bsum, rowptr, nB, N);
  scan3_kernel<<<nB, 256, 0, stream>>>(cnt, bsum, rowptr, N);
  // 6. CSR fill
  fill_kernel<<<(E + 255) / 256, 256, 0, stream>>>(src, dstE, rowptr, cursor, eidx, E);
  // 7. W prep, both layers
  cvt_w_kernel<<<(L * DIM * 256 + 255) / 256, 256, 0, stream>>>(W_l, W_r, Wth, Wtl, L);

  for (int l = 0; l < L; ++l) {
    gather_kernel<<<(N * 16 + 255) / 256, 256, 0, stream>>>(xh, rowptr, eidx, aggh, N);
    gemm_mfma_kernel<<<(N + 127) / 128, 256, 0, stream>>>(aggh, xh,
        Wth + (size_t)l * DIM * 256, Wtl + (size_t)l * DIM * 256,
        b_l + (size_t)l * DIM, h, sums + (size_t)l * 2 * DIM, N);
    if (l < L - 1) {
      bn_relu_kernel<<<(N * (DIM / 8) + 255) / 256, 256, 0, stream>>>(
          h, sums + (size_t)l * 2 * DIM, gamma + (size_t)l * DIM,
          beta + (size_t)l * DIM, xh, N);
    } else {
      pool_fused_kernel<<<(N + POOL_ROWS - 1) / POOL_ROWS, 256, 0, stream>>>(
          h, sums + (size_t)l * 2 * DIM, gamma + (size_t)l * DIM,
          beta + (size_t)l * DIM, batch, outsum, N);
      pool_div_kernel<<<(G * DIM + 255) / 256, 256, 0, stream>>>(outsum, batch, out, N, G);
    }
  }
}